// Round 16
// baseline (3396.074 us; speedup 1.0000x reference)
//
#include <hip/hip_runtime.h>
#include <math.h>

// ---- problem constants --------------------------------------------------
constexpr int kL = 12, kD = 768, kH = 12, kV = 51865, kSA = 1500;
constexpr int kB = 2, kT = 192, kMC = 256, kDH = 64;
constexpr float kScale = 0.125f;      // DH^-0.5
constexpr float kEps = 1e-5f;
constexpr int kR = kB * kMC;          // 512 rows through the layer stack
constexpr int kSLDc = 1504;           // cross score row stride (elements)

// ---- d_out layout (flat float32, reference return order) ---------------
constexpr size_t SZ_LOGITS = (size_t)kB * kT * kV;
constexpr size_t SZ_CQK    = (size_t)kL * kB * kH * kT * kSA;
constexpr size_t SZ_MKV    = (size_t)2 * kL * kB * kMC * kD;
constexpr size_t OFF_CQK = SZ_LOGITS;
constexpr size_t OFF_MKV = OFF_CQK + SZ_CQK;
constexpr size_t OFF_CKV = OFF_MKV + SZ_MKV;

typedef float f32x4v __attribute__((ext_vector_type(4)));
typedef unsigned short us8v __attribute__((ext_vector_type(8)));
typedef unsigned short us4v __attribute__((ext_vector_type(4)));
typedef unsigned int   u32x4 __attribute__((ext_vector_type(4)));

static __device__ __forceinline__ unsigned short f2bf(float f) {
    unsigned int u = __float_as_uint(f);
    u += 0x7fffu + ((u >> 16) & 1u);          // round-to-nearest-even
    return (unsigned short)(u >> 16);
}

// packed f32x2 -> bf16x2 (RNE), low half from `lo`
static __device__ __forceinline__ unsigned int f2bf2(float lo, float hi) {
    unsigned int r;
    asm("v_cvt_pk_bf16_f32 %0, %1, %2" : "=v"(r) : "v"(lo), "v"(hi));
    return r;
}

static __device__ __forceinline__ float bf2f(unsigned short u) {
    return __uint_as_float((unsigned int)u << 16);
}

static __device__ __forceinline__ f32x4v mfma_bf16(us8v a, us8v b, f32x4v c) {
    asm("v_mfma_f32_16x16x32_bf16 %0, %1, %2, %0" : "+v"(c) : "v"(a), "v"(b));
    return c;
}

// ========================================================================
// embedding
// ========================================================================
__global__ void k_embed(const int* __restrict__ x, const float* __restrict__ tok,
                        const float* __restrict__ pos, float* __restrict__ h)
{
    int idx = blockIdx.x * 256 + threadIdx.x;
    int d = idx % kD;
    int t = (idx / kD) % kMC;
    int b = idx / (kD * kMC);
    float v = 0.f;
    if (t < kT) {
        int tokid = x[b * kT + t];
        v = tok[(size_t)tokid * kD + d] + pos[(size_t)t * kD + d];
    }
    h[idx] = v;
}

// ========================================================================
// Final LayerNorm (rows t<T, compacted) -> bf16
// ========================================================================
__global__ void k_finalln(const float* __restrict__ h, const float* __restrict__ g,
                          const float* __restrict__ bb, unsigned short* __restrict__ out)
{
    int r = blockIdx.x;                 // 0..kB*kT
    int b = r / kT, tt = r % kT;
    const float* xr = h + (size_t)(b * kMC + tt) * kD;
    int t = threadIdx.x;
    float x0 = xr[t], x1 = xr[t + 256], x2 = xr[t + 512];
    float s  = x0 + x1 + x2;
    float sq = x0 * x0 + x1 * x1 + x2 * x2;
    __shared__ float red[8];
    for (int o = 32; o > 0; o >>= 1) { s += __shfl_down(s, o); sq += __shfl_down(sq, o); }
    int w = t >> 6;
    if ((t & 63) == 0) { red[w] = s; red[4 + w] = sq; }
    __syncthreads();
    s  = red[0] + red[1] + red[2] + red[3];
    sq = red[4] + red[5] + red[6] + red[7];
    float m   = s * (1.f / kD);
    float var = sq * (1.f / kD) - m * m;
    float rs  = rsqrtf(var + kEps);
    unsigned short* orow = out + (size_t)r * kD;
    orow[t]       = f2bf((x0 - m) * rs * g[t]       + bb[t]);
    orow[t + 256] = f2bf((x1 - m) * rs * g[t + 256] + bb[t + 256]);
    orow[t + 512] = f2bf((x2 - m) * rs * g[t + 512] + bb[t + 512]);
}

// ========================================================================
// bf16-MFMA GEMM (BM=64), triple-buffered, prefetch distance 2.
// Used only for the fp32-A cross-K/V init batch. (round-12 proven)
// ========================================================================
struct GEntry { const float* W; const float* bias; const float* res; void* out; };
struct GBatch { GEntry e[24]; };

template <int ABF, int OBF>
__global__ __launch_bounds__(256)
void gemm_t(const void* __restrict__ Av, GBatch gb, int M, int N, int K,
            int dogelu)
{
    constexpr int LD = 72;
    __shared__ unsigned short As[3][64][LD];
    __shared__ unsigned short Ws[3][64][LD];
    const GEntry ge = gb.e[blockIdx.z];
    const float* __restrict__ W = ge.W;
    int bn = blockIdx.y * 64;
    int bm = blockIdx.x * 64;
    int tid = threadIdx.x;
    int wid = tid >> 6, lane = tid & 63;
    int wm = (wid >> 1) * 32, wn = (wid & 1) * 32;
    int l15 = lane & 15, lg = lane >> 4;
    int r = tid >> 2, cq = (tid & 3) * 16;
    int gr = bm + r, gc = bn + r;

    auto load_a = [&](int k0, u32x4& p0, u32x4& p1) {
        p0 = (u32x4){}; p1 = (u32x4){};
        if (ABF) {
            if (gr < M) {
                const unsigned short* ar =
                    (const unsigned short*)Av + (size_t)gr * K + k0 + cq;
                p0 = *(const u32x4*)ar;
                p1 = *(const u32x4*)(ar + 8);
            }
        } else {
            if (gr < M) {
                const float* ar = (const float*)Av + (size_t)gr * K + k0 + cq;
                float4 v0 = *(const float4*)(ar);
                float4 v1 = *(const float4*)(ar + 4);
                float4 v2 = *(const float4*)(ar + 8);
                float4 v3 = *(const float4*)(ar + 12);
                p0[0] = f2bf2(v0.x, v0.y); p0[1] = f2bf2(v0.z, v0.w);
                p0[2] = f2bf2(v1.x, v1.y); p0[3] = f2bf2(v1.z, v1.w);
                p1[0] = f2bf2(v2.x, v2.y); p1[1] = f2bf2(v2.z, v2.w);
                p1[2] = f2bf2(v3.x, v3.y); p1[3] = f2bf2(v3.z, v3.w);
            }
        }
    };
    auto load_w = [&](int k0, u32x4& p0, u32x4& p1) {
        p0 = (u32x4){}; p1 = (u32x4){};
        if (gc < N) {
            const float* wr = W + (size_t)gc * K + k0 + cq;
            float4 v0 = *(const float4*)(wr);
            float4 v1 = *(const float4*)(wr + 4);
            float4 v2 = *(const float4*)(wr + 8);
            float4 v3 = *(const float4*)(wr + 12);
            p0[0] = f2bf2(v0.x, v0.y); p0[1] = f2bf2(v0.z, v0.w);
            p0[2] = f2bf2(v1.x, v1.y); p0[3] = f2bf2(v1.z, v1.w);
            p1[0] = f2bf2(v2.x, v2.y); p1[1] = f2bf2(v2.z, v2.w);
            p1[2] = f2bf2(v3.x, v3.y); p1[3] = f2bf2(v3.z, v3.w);
        }
    };
    auto stage = [&](int buf, u32x4 a0, u32x4 a1, u32x4 w0, u32x4 w1) {
        *(u32x4*)&As[buf][r][cq]     = a0;
        *(u32x4*)&As[buf][r][cq + 8] = a1;
        *(u32x4*)&Ws[buf][r][cq]     = w0;
        *(u32x4*)&Ws[buf][r][cq + 8] = w1;
    };

    f32x4v acc00 = {}, acc01 = {}, acc10 = {}, acc11 = {};
    auto domfma = [&](int buf) {
        #pragma unroll
        for (int kc = 0; kc < 2; ++kc) {
            us8v af0 = *(const us8v*)&As[buf][wm + l15][kc * 32 + lg * 8];
            us8v af1 = *(const us8v*)&As[buf][wm + 16 + l15][kc * 32 + lg * 8];
            us8v wf0 = *(const us8v*)&Ws[buf][wn + l15][kc * 32 + lg * 8];
            us8v wf1 = *(const us8v*)&Ws[buf][wn + 16 + l15][kc * 32 + lg * 8];
            acc00 = mfma_bf16(af0, wf0, acc00);
            acc01 = mfma_bf16(af0, wf1, acc01);
            acc10 = mfma_bf16(af1, wf0, acc10);
            acc11 = mfma_bf16(af1, wf1, acc11);
        }
    };

    u32x4 a0A, a1A, w0A, w1A, a0B, a1B, w0B, w1B;
    load_a(0, a0A, a1A); load_w(0, w0A, w1A);
    stage(0, a0A, a1A, w0A, w1A);
    load_a(64, a0B, a1B); load_w(64, w0B, w1B);
    __syncthreads();

    int cur = 0;
    for (int k0 = 0; k0 < K; k0 += 128) {
        int n1 = cur + 1; if (n1 == 3) n1 = 0;
        int n2 = n1 + 1; if (n2 == 3) n2 = 0;
        if (k0 + 128 < K) { load_a(k0 + 128, a0A, a1A); load_w(k0 + 128, w0A, w1A); }
        domfma(cur);
        stage(n1, a0B, a1B, w0B, w1B);
        __syncthreads();
        if (k0 + 192 < K) { load_a(k0 + 192, a0B, a1B); load_w(k0 + 192, w0B, w1B); }
        domfma(n1);
        if (k0 + 128 < K) {
            stage(n2, a0A, a1A, w0A, w1A);
            __syncthreads();
        }
        cur = n2;
    }

    const float* bias = ge.bias;
    const float* res  = ge.res;
    f32x4v accs[2][2] = { { acc00, acc01 }, { acc10, acc11 } };
    #pragma unroll
    for (int fi = 0; fi < 2; ++fi) {
        #pragma unroll
        for (int fj = 0; fj < 2; ++fj) {
            int col = bn + wn + fj * 16 + l15;
            if (col >= N) continue;
            float bv = bias ? bias[col] : 0.f;
            #pragma unroll
            for (int rr = 0; rr < 4; ++rr) {
                int row = bm + wm + fi * 16 + lg * 4 + rr;
                if (row >= M) continue;
                float v = accs[fi][fj][rr] + bv;
                if (dogelu) v = 0.5f * v * (1.f + erff(v * 0.70710678118654752f));
                if (OBF) {
                    ((unsigned short*)ge.out)[(size_t)row * N + col] = f2bf(v);
                } else {
                    if (res) v += res[(size_t)row * N + col];
                    ((float*)ge.out)[(size_t)row * N + col] = v;
                }
            }
        }
    }
}

// ========================================================================
// bf16-MFMA GEMM, BM=32/BN=64, triple-buffered, prefetch distance 2.
// AMODE 0: A bf16. AMODE 1: A fp32 + FUSED LayerNorm (lnG/lnB; K==768).
// Stats pre-pass: 8 thr/row over 96-contiguous floats + 3-step shuffle.
// LN applied in fp32 during staging, then RNE->bf16 (same rounding point
// as the old standalone k_ln).
// ========================================================================
template <int AMODE, int OBF>
__global__ __launch_bounds__(256)
void gemm32(const void* __restrict__ Av, GBatch gb, int M, int N, int K,
            int dogelu, const float* __restrict__ lnG,
            const float* __restrict__ lnB)
{
    constexpr int LD = 72;
    __shared__ unsigned short As[3][32][LD];
    __shared__ unsigned short Ws[3][64][LD];
    __shared__ float lnm[32], lnr[32];
    const GEntry ge = gb.e[blockIdx.z];
    const float* __restrict__ W = ge.W;
    int bn = blockIdx.y * 64;
    int bm = blockIdx.x * 32;
    int tid = threadIdx.x;
    int wid = tid >> 6, lane = tid & 63;
    int wr = (wid >> 1) * 16, wc = (wid & 1) * 32;
    int l15 = lane & 15, lg = lane >> 4;
    int ra = tid >> 3, ca = (tid & 7) * 8;    // A staging: 32 rows x 64 k
    int rw = tid >> 2, cw = (tid & 3) * 16;   // W staging: 64 rows x 64 k
    int gr = bm + ra, gc = bn + rw;

    float lnm_r = 0.f, lnr_r = 0.f;
    if (AMODE == 1) {
        // per-row LN stats (K == 768): row = ra, part = tid&7 -> 96 floats
        int part = tid & 7;
        float s = 0.f, sq = 0.f;
        if (gr < M) {
            const float* ar = (const float*)Av + (size_t)gr * K + part * 96;
            #pragma unroll 8
            for (int i = 0; i < 96; i += 4) {
                float4 v = *(const float4*)(ar + i);
                s  += v.x + v.y + v.z + v.w;
                sq += v.x * v.x + v.y * v.y + v.z * v.z + v.w * v.w;
            }
        }
        s += __shfl_xor(s, 1); sq += __shfl_xor(sq, 1);
        s += __shfl_xor(s, 2); sq += __shfl_xor(sq, 2);
        s += __shfl_xor(s, 4); sq += __shfl_xor(sq, 4);
        if (part == 0) {
            float m = s * (1.f / 768.f);
            lnm[ra] = m;
            lnr[ra] = rsqrtf(sq * (1.f / 768.f) - m * m + kEps);
        }
        __syncthreads();
        lnm_r = lnm[ra];
        lnr_r = lnr[ra];
    }

    auto load_a = [&](int k0, us8v& p) {
        p = (us8v){};
        if (gr < M) {
            if (AMODE == 0) {
                p = *(const us8v*)((const unsigned short*)Av +
                                   (size_t)gr * K + k0 + ca);
            } else {
                const float* ar = (const float*)Av + (size_t)gr * K + k0 + ca;
                float4 v0 = *(const float4*)(ar);
                float4 v1 = *(const float4*)(ar + 4);
                const float* gp = lnG + k0 + ca;
                const float* bp = lnB + k0 + ca;
                float4 g0 = *(const float4*)(gp);
                float4 g1 = *(const float4*)(gp + 4);
                float4 b0 = *(const float4*)(bp);
                float4 b1 = *(const float4*)(bp + 4);
                float a0 = (v0.x - lnm_r) * lnr_r * g0.x + b0.x;
                float a1 = (v0.y - lnm_r) * lnr_r * g0.y + b0.y;
                float a2 = (v0.z - lnm_r) * lnr_r * g0.z + b0.z;
                float a3 = (v0.w - lnm_r) * lnr_r * g0.w + b0.w;
                float a4 = (v1.x - lnm_r) * lnr_r * g1.x + b1.x;
                float a5 = (v1.y - lnm_r) * lnr_r * g1.y + b1.y;
                float a6 = (v1.z - lnm_r) * lnr_r * g1.z + b1.z;
                float a7 = (v1.w - lnm_r) * lnr_r * g1.w + b1.w;
                u32x4 q;
                q[0] = f2bf2(a0, a1); q[1] = f2bf2(a2, a3);
                q[2] = f2bf2(a4, a5); q[3] = f2bf2(a6, a7);
                p = *(us8v*)&q;
            }
        }
    };
    auto load_w = [&](int k0, u32x4& p0, u32x4& p1) {
        p0 = (u32x4){}; p1 = (u32x4){};
        if (gc < N) {
            const float* wrp = W + (size_t)gc * K + k0 + cw;
            float4 v0 = *(const float4*)(wrp);
            float4 v1 = *(const float4*)(wrp + 4);
            float4 v2 = *(const float4*)(wrp + 8);
            float4 v3 = *(const float4*)(wrp + 12);
            p0[0] = f2bf2(v0.x, v0.y); p0[1] = f2bf2(v0.z, v0.w);
            p0[2] = f2bf2(v1.x, v1.y); p0[3] = f2bf2(v1.z, v1.w);
            p1[0] = f2bf2(v2.x, v2.y); p1[1] = f2bf2(v2.z, v2.w);
            p1[2] = f2bf2(v3.x, v3.y); p1[3] = f2bf2(v3.z, v3.w);
        }
    };
    auto stage = [&](int buf, us8v a, u32x4 w0, u32x4 w1) {
        *(us8v*)&As[buf][ra][ca]      = a;
        *(u32x4*)&Ws[buf][rw][cw]     = w0;
        *(u32x4*)&Ws[buf][rw][cw + 8] = w1;
    };

    f32x4v acc0 = {}, acc1 = {};
    auto domfma = [&](int buf) {
        #pragma unroll
        for (int kc = 0; kc < 2; ++kc) {
            us8v af  = *(const us8v*)&As[buf][wr + l15][kc * 32 + lg * 8];
            us8v wf0 = *(const us8v*)&Ws[buf][wc + l15][kc * 32 + lg * 8];
            us8v wf1 = *(const us8v*)&Ws[buf][wc + 16 + l15][kc * 32 + lg * 8];
            acc0 = mfma_bf16(af, wf0, acc0);
            acc1 = mfma_bf16(af, wf1, acc1);
        }
    };

    us8v aA, aB;
    u32x4 w0A, w1A, w0B, w1B;
    load_a(0, aA); load_w(0, w0A, w1A);
    stage(0, aA, w0A, w1A);
    load_a(64, aB); load_w(64, w0B, w1B);
    __syncthreads();

    int cur = 0;
    for (int k0 = 0; k0 < K; k0 += 128) {
        int n1 = cur + 1; if (n1 == 3) n1 = 0;
        int n2 = n1 + 1; if (n2 == 3) n2 = 0;
        if (k0 + 128 < K) { load_a(k0 + 128, aA); load_w(k0 + 128, w0A, w1A); }
        domfma(cur);
        stage(n1, aB, w0B, w1B);
        __syncthreads();
        if (k0 + 192 < K) { load_a(k0 + 192, aB); load_w(k0 + 192, w0B, w1B); }
        domfma(n1);
        if (k0 + 128 < K) {
            stage(n2, aA, w0A, w1A);
            __syncthreads();
        }
        cur = n2;
    }

    const float* bias = ge.bias;
    const float* res  = ge.res;
    f32x4v accs[2] = { acc0, acc1 };
    #pragma unroll
    for (int fj = 0; fj < 2; ++fj) {
        int col = bn + wc + fj * 16 + l15;
        if (col >= N) continue;
        float bv = bias ? bias[col] : 0.f;
        #pragma unroll
        for (int rr = 0; rr < 4; ++rr) {
            int row = bm + wr + lg * 4 + rr;
            if (row >= M) continue;
            float v = accs[fj][rr] + bv;
            if (dogelu) v = 0.5f * v * (1.f + erff(v * 0.70710678118654752f));
            if (OBF) {
                ((unsigned short*)ge.out)[(size_t)row * N + col] = f2bf(v);
            } else {
                if (res) v += res[(size_t)row * N + col];
                ((float*)ge.out)[(size_t)row * N + col] = v;
            }
        }
    }
}

// ========================================================================
// Logits GEMM: k0-outer / m-tile-inner, W double-buffered. (round 12)
// ========================================================================
__global__ __launch_bounds__(256)
void k_logits(const unsigned short* __restrict__ A, const float* __restrict__ W,
              float* __restrict__ out)
{
    constexpr int LD = 72;
    __shared__ unsigned short As[64][LD];
    __shared__ unsigned short Ws[2][64][LD];
    int bn = blockIdx.x * 64;
    int tid = threadIdx.x;
    int wid = tid >> 6, lane = tid & 63;
    int wm = (wid >> 1) * 32, wn = (wid & 1) * 32;
    int l15 = lane & 15, lg = lane >> 4;
    int r = tid >> 2, cq = (tid & 3) * 16;
    int gc = bn + r;

    auto load_w = [&](int k0, u32x4& p0, u32x4& p1) {
        p0 = (u32x4){}; p1 = (u32x4){};
        if (gc < kV) {
            const float* wr = W + (size_t)gc * kD + k0 + cq;
            float4 v0 = *(const float4*)(wr);
            float4 v1 = *(const float4*)(wr + 4);
            float4 v2 = *(const float4*)(wr + 8);
            float4 v3 = *(const float4*)(wr + 12);
            p0[0] = f2bf2(v0.x, v0.y); p0[1] = f2bf2(v0.z, v0.w);
            p0[2] = f2bf2(v1.x, v1.y); p0[3] = f2bf2(v1.z, v1.w);
            p1[0] = f2bf2(v2.x, v2.y); p1[1] = f2bf2(v2.z, v2.w);
            p1[2] = f2bf2(v3.x, v3.y); p1[3] = f2bf2(v3.z, v3.w);
        }
    };

    f32x4v acc[6][4];
    #pragma unroll
    for (int i = 0; i < 6; ++i)
        #pragma unroll
        for (int j = 0; j < 4; ++j) acc[i][j] = (f32x4v){};

    u32x4 rw0, rw1;
    load_w(0, rw0, rw1);
    *(u32x4*)&Ws[0][r][cq]     = rw0;
    *(u32x4*)&Ws[0][r][cq + 8] = rw1;
    __syncthreads();

    int cur = 0;
    for (int k0 = 0; k0 < kD; k0 += 64) {
        bool more = (k0 + 64) < kD;
        if (more) load_w(k0 + 64, rw0, rw1);
        #pragma unroll
        for (int mt = 0; mt < 6; ++mt) {
            {
                const unsigned short* ar = A + (size_t)(mt * 64 + r) * kD + k0 + cq;
                us8v v0 = *(const us8v*)ar;
                us8v v1 = *(const us8v*)(ar + 8);
                *(us8v*)&As[r][cq]     = v0;
                *(us8v*)&As[r][cq + 8] = v1;
            }
            __syncthreads();
            #pragma unroll
            for (int kc = 0; kc < 2; ++kc) {
                us8v af0 = *(const us8v*)&As[wm + l15][kc * 32 + lg * 8];
                us8v af1 = *(const us8v*)&As[wm + 16 + l15][kc * 32 + lg * 8];
                us8v wf0 = *(const us8v*)&Ws[cur][wn + l15][kc * 32 + lg * 8];
                us8v wf1 = *(const us8v*)&Ws[cur][wn + 16 + l15][kc * 32 + lg * 8];
                acc[mt][0] = mfma_bf16(af0, wf0, acc[mt][0]);
                acc[mt][1] = mfma_bf16(af0, wf1, acc[mt][1]);
                acc[mt][2] = mfma_bf16(af1, wf0, acc[mt][2]);
                acc[mt][3] = mfma_bf16(af1, wf1, acc[mt][3]);
            }
            __syncthreads();
        }
        if (more) {
            int nxt = cur ^ 1;
            *(u32x4*)&Ws[nxt][r][cq]     = rw0;
            *(u32x4*)&Ws[nxt][r][cq + 8] = rw1;
            cur = nxt;
        }
    }
    #pragma unroll
    for (int mt = 0; mt < 6; ++mt) {
        #pragma unroll
        for (int fi = 0; fi < 2; ++fi) {
            #pragma unroll
            for (int fj = 0; fj < 2; ++fj) {
                int col = bn + wn + fj * 16 + l15;
                if (col >= kV) continue;
                #pragma unroll
                for (int rr = 0; rr < 4; ++rr) {
                    int row = mt * 64 + wm + fi * 16 + lg * 4 + rr;
                    out[(size_t)row * kV + col] = acc[mt][fi * 2 + fj][rr];
                }
            }
        }
    }
}

// ========================================================================
// Attention scores via MFMA -> bf16 scratch (+fp32 cqk for cross) (rnd 12)
// ========================================================================
template <int QBF>
__global__ __launch_bounds__(256)
void k_scores(const void* __restrict__ qv, const float* __restrict__ kk,
              unsigned short* __restrict__ sws, float* __restrict__ cqk,
              int Nk, int sld, int selfmask, int kPerB)
{
    constexpr int LD = 72;
    __shared__ unsigned short As[64][LD];
    __shared__ unsigned short Ks[64][LD];
    int z = blockIdx.z, b = z / kH, h = z % kH;
    int bm = blockIdx.x * 64, bn = blockIdx.y * 64;
    const float* kbase = kk + (kPerB ? (size_t)b * kMC * kD : 0) + (size_t)h * kDH;

    int tid = threadIdx.x;
    int r = tid >> 2, c0 = (tid & 3) * 16;
    {
        if (QBF) {
            const unsigned short* q = (const unsigned short*)qv;
            const unsigned short* qr =
                q + (size_t)(b * kMC + bm + r) * kD + h * kDH + c0;
            *(us8v*)&As[r][c0]     = *(const us8v*)qr;
            *(us8v*)&As[r][c0 + 8] = *(const us8v*)(qr + 8);
        } else {
            const float* q = (const float*)qv;
            const float* qr = q + (size_t)(b * kMC + bm + r) * kD + h * kDH + c0;
            float4 v0 = *(const float4*)(qr);
            float4 v1 = *(const float4*)(qr + 4);
            float4 v2 = *(const float4*)(qr + 8);
            float4 v3 = *(const float4*)(qr + 12);
            u32x4 p0, p1;
            p0[0] = f2bf2(v0.x, v0.y); p0[1] = f2bf2(v0.z, v0.w);
            p0[2] = f2bf2(v1.x, v1.y); p0[3] = f2bf2(v1.z, v1.w);
            p1[0] = f2bf2(v2.x, v2.y); p1[1] = f2bf2(v2.z, v2.w);
            p1[2] = f2bf2(v3.x, v3.y); p1[3] = f2bf2(v3.z, v3.w);
            *(u32x4*)&As[r][c0]     = p0;
            *(u32x4*)&As[r][c0 + 8] = p1;
        }
        int gk = bn + r;
        if (gk < Nk) {
            const float* kr = kbase + (size_t)gk * kD + c0;
            float4 v0 = *(const float4*)(kr);
            float4 v1 = *(const float4*)(kr + 4);
            float4 v2 = *(const float4*)(kr + 8);
            float4 v3 = *(const float4*)(kr + 12);
            u32x4 p0, p1;
            p0[0] = f2bf2(v0.x, v0.y); p0[1] = f2bf2(v0.z, v0.w);
            p0[2] = f2bf2(v1.x, v1.y); p0[3] = f2bf2(v1.z, v1.w);
            p1[0] = f2bf2(v2.x, v2.y); p1[1] = f2bf2(v2.z, v2.w);
            p1[2] = f2bf2(v3.x, v3.y); p1[3] = f2bf2(v3.z, v3.w);
            *(u32x4*)&Ks[r][c0]     = p0;
            *(u32x4*)&Ks[r][c0 + 8] = p1;
        } else {
            u32x4 zz = {};
            *(u32x4*)&Ks[r][c0]     = zz;
            *(u32x4*)&Ks[r][c0 + 8] = zz;
        }
    }
    __syncthreads();

    int wid = tid >> 6, lane = tid & 63;
    int wm = (wid >> 1) * 32, wn = (wid & 1) * 32;
    int l15 = lane & 15, lg = lane >> 4;

    f32x4v acc[2][2] = {};
    #pragma unroll
    for (int kc = 0; kc < 2; ++kc) {
        us8v a0 = *(const us8v*)&As[wm + l15][kc * 32 + lg * 8];
        us8v a1 = *(const us8v*)&As[wm + 16 + l15][kc * 32 + lg * 8];
        us8v b0 = *(const us8v*)&Ks[wn + l15][kc * 32 + lg * 8];
        us8v b1 = *(const us8v*)&Ks[wn + 16 + l15][kc * 32 + lg * 8];
        acc[0][0] = mfma_bf16(a0, b0, acc[0][0]);
        acc[0][1] = mfma_bf16(a0, b1, acc[0][1]);
        acc[1][0] = mfma_bf16(a1, b0, acc[1][0]);
        acc[1][1] = mfma_bf16(a1, b1, acc[1][1]);
    }

    #pragma unroll
    for (int fm = 0; fm < 2; ++fm) {
        #pragma unroll
        for (int fn = 0; fn < 2; ++fn) {
            int gj = bn + wn + fn * 16 + l15;
            if (gj >= Nk) continue;
            #pragma unroll
            for (int rr = 0; rr < 4; ++rr) {
                int gi = bm + wm + fm * 16 + lg * 4 + rr;
                float val = acc[fm][fn][rr] * kScale;
                if (cqk && gi < kT)
                    cqk[(((size_t)(b * kH + h)) * kT + gi) * kSA + gj] = val;
                if (selfmask && (gj > gi || gj >= kT)) val = -1e30f;
                sws[((size_t)z * kMC + gi) * sld + gj] = f2bf(val);
            }
        }
    }
}

// ========================================================================
// Softmax + PV via MFMA, bf16 scores. Block = 16 q-rows of one z (rnd 12).
// ========================================================================
constexpr int kCH  = 128;   // key chunk
constexpr int kLDK = 136;   // bf16 k-stride
__global__ __launch_bounds__(256)
void k_pv(const unsigned short* __restrict__ sws, const float* __restrict__ vv,
          unsigned short* __restrict__ o, int Nk, int sld, int vPerB)
{
    __shared__ unsigned short Pb[16][kLDK];
    __shared__ unsigned short Vt[64][kLDK];
    __shared__ float smx[16], sinv[16];
    int z = blockIdx.y, b = z / kH, h = z % kH;
    int i0 = blockIdx.x * 16;
    int t = threadIdx.x, wid = t >> 6, lane = t & 63;
    int l15 = lane & 15, lg = lane >> 4;
    const float* vbase = vv + (vPerB ? (size_t)b * kMC * kD : 0) + (size_t)h * kDH;

    // ---- pass 1: row max & inv-sum (vectorized 8-wide reads) ----
    for (int r2 = wid; r2 < 16; r2 += 4) {
        const unsigned short* srow2 = sws + ((size_t)z * kMC + i0 + r2) * sld;
        float mx = -3e38f;
        for (int j0 = lane * 8; j0 < Nk; j0 += 512) {
            us8v v = *(const us8v*)&srow2[j0];
            #pragma unroll
            for (int e = 0; e < 8; ++e)
                if (j0 + e < Nk) mx = fmaxf(mx, bf2f(v[e]));
        }
        for (int off = 32; off > 0; off >>= 1) mx = fmaxf(mx, __shfl_xor(mx, off));
        float sum = 0.f;
        for (int j0 = lane * 8; j0 < Nk; j0 += 512) {
            us8v v = *(const us8v*)&srow2[j0];
            #pragma unroll
            for (int e = 0; e < 8; ++e)
                if (j0 + e < Nk) sum += expf(bf2f(v[e]) - mx);
        }
        for (int off = 32; off > 0; off >>= 1) sum += __shfl_xor(sum, off);
        if (lane == 0) { smx[r2] = mx; sinv[r2] = 1.f / sum; }
    }
    __syncthreads();

    // ---- pass 2: chunked MFMA PV ----
    int pr = t >> 4;                 // P-stage row 0..15
    int jb = (t & 15) * 8;           // P-stage key base within chunk
    const unsigned short* srow = sws + ((size_t)z * kMC + i0 + pr) * sld;
    float mxv = smx[pr];

    f32x4v acc = {};
    for (int k0 = 0; k0 < Nk; k0 += kCH) {
        #pragma unroll
        for (int u = 0; u < 4; ++u) {
            int flat = t + u * 256;
            int kr = (flat >> 4) * 2;
            int c4 = flat & 15;
            float4 va = {0,0,0,0}, vb2 = {0,0,0,0};
            if (k0 + kr < Nk)
                va = *(const float4*)(vbase + (size_t)(k0 + kr) * kD + c4 * 4);
            if (k0 + kr + 1 < Nk)
                vb2 = *(const float4*)(vbase + (size_t)(k0 + kr + 1) * kD + c4 * 4);
            *(unsigned int*)&Vt[c4 * 4 + 0][kr] = f2bf2(va.x, vb2.x);
            *(unsigned int*)&Vt[c4 * 4 + 1][kr] = f2bf2(va.y, vb2.y);
            *(unsigned int*)&Vt[c4 * 4 + 2][kr] = f2bf2(va.z, vb2.z);
            *(unsigned int*)&Vt[c4 * 4 + 3][kr] = f2bf2(va.w, vb2.w);
        }
        {
            us8v praw = *(const us8v*)&srow[k0 + jb];
            #pragma unroll
            for (int u = 0; u < 8; u += 2) {
                int gj0 = k0 + jb + u;
                float e0 = (gj0     < Nk) ? expf(bf2f(praw[u])     - mxv) : 0.f;
                float e1 = (gj0 + 1 < Nk) ? expf(bf2f(praw[u + 1]) - mxv) : 0.f;
                *(unsigned int*)&Pb[pr][jb + u] = f2bf2(e0, e1);
            }
        }
        __syncthreads();
        #pragma unroll
        for (int kc = 0; kc < 4; ++kc) {
            us8v a  = *(const us8v*)&Pb[l15][kc * 32 + lg * 8];
            us8v bf = *(const us8v*)&Vt[wid * 16 + l15][kc * 32 + lg * 8];
            acc = mfma_bf16(a, bf, acc);
        }
        __syncthreads();
    }

    #pragma unroll
    for (int rr = 0; rr < 4; ++rr) {
        int row = lg * 4 + rr;
        float v = acc[rr] * sinv[row];
        o[(size_t)(b * kMC + i0 + row) * kD + h * kDH + wid * 16 + l15] = f2bf(v);
    }
}

// ========================================================================
extern "C" void kernel_launch(void* const* d_in, const int* in_sizes, int n_in,
                              void* d_out, int out_size, void* d_ws, size_t ws_size,
                              hipStream_t stream)
{
    const int*   x   = (const int*)  d_in[0];
    const float* xa  = (const float*)d_in[1];
    const float* tok = (const float*)d_in[4];
    const float* pos = (const float*)d_in[5];
    const float* attn_ln_g  = (const float*)d_in[6];
    const float* attn_ln_b  = (const float*)d_in[7];
    const float* attn_q_w   = (const float*)d_in[8];
    const float* attn_q_b   = (const float*)d_in[9];
    const float* attn_k_w   = (const float*)d_in[10];
    const float* attn_v_w   = (const float*)d_in[11];
    const float* attn_v_b   = (const float*)d_in[12];
    const float* attn_o_w   = (const float*)d_in[13];
    const float* attn_o_b   = (const float*)d_in[14];
    const float* cross_ln_g = (const float*)d_in[15];
    const float* cross_ln_b = (const float*)d_in[16];
    const float* cross_q_w  = (const float*)d_in[17];
    const float* cross_q_b  = (const float*)d_in[18];
    const float* cross_k_w  = (const float*)d_in[19];
    const float* cross_v_w  = (const float*)d_in[20];
    const float* cross_v_b  = (const float*)d_in[21];
    const float* cross_o_w  = (const float*)d_in[22];
    const float* cross_o_b  = (const float*)d_in[23];
    const float* mlp_ln_g   = (const float*)d_in[24];
    const float* mlp_ln_b   = (const float*)d_in[25];
    const float* mlp_w1     = (const float*)d_in[26];
    const float* mlp_b1     = (const float*)d_in[27];
    const float* mlp_w2     = (const float*)d_in[28];
    const float* mlp_b2     = (const float*)d_in[29];
    const float* ln_g       = (const float*)d_in[30];
    const float* ln_b       = (const float*)d_in[31];

    float* out = (float*)d_out;
    float* h    = (float*)d_ws;                          // 512*768 f32
    float* qws  = h   + (size_t)kR * kD;                 // 512*768 f32 (self q)
    unsigned short* sS    = (unsigned short*)(qws + (size_t)kR * kD); // bf16 scores
    unsigned short* qb16  = sS   + (size_t)kB * kH * kMC * kSLDc;     // cross q bf16
    unsigned short* o16   = qb16 + (size_t)kR * kD;      // attn out bf16
    unsigned short* hid16 = o16  + (size_t)kR * kD;      // MLP hidden bf16
    unsigned short* yF16  = hid16 + (size_t)kR * 4 * kD; // final LN bf16

    k_embed<<<kB * kMC * kD / 256, 256, 0, stream>>>(x, tok, pos, h);

    // all cross K/V projections (layer-invariant input xa) in ONE launch
    {
        GBatch gc{};
        for (int l = 0; l < kL; ++l) {
            gc.e[2 * l]     = { cross_k_w + (size_t)l * kD * kD, nullptr, nullptr,
                                out + OFF_CKV + (size_t)(2 * l) * kSA * kD };
            gc.e[2 * l + 1] = { cross_v_w + (size_t)l * kD * kD, cross_v_b + (size_t)l * kD,
                                nullptr,
                                out + OFF_CKV + (size_t)(2 * l + 1) * kSA * kD };
        }
        gemm_t<0, 0><<<dim3((kSA + 63) / 64, kD / 64, 2 * kL), 256, 0, stream>>>(
            xa, gc, kSA, kD, kD, 0);
    }

    for (int l = 0; l < kL; ++l) {
        size_t dd = (size_t)l * kD * kD;
        float* kbuf  = out + OFF_MKV + (size_t)(2 * l)     * kB * kMC * kD;
        float* vbuf  = out + OFF_MKV + (size_t)(2 * l + 1) * kB * kMC * kD;
        float* ckbuf = out + OFF_CKV + (size_t)(2 * l)     * kSA * kD;
        float* cvbuf = out + OFF_CKV + (size_t)(2 * l + 1) * kSA * kD;
        float* cqk   = out + OFF_CQK + (size_t)l * kB * kH * kT * kSA;

        // --- self attention (LN fused into QKV staging) ---
        {
            GBatch g3{};
            g3.e[0] = { attn_q_w + dd, attn_q_b + (size_t)l * kD, nullptr, qws };
            g3.e[1] = { attn_k_w + dd, nullptr,                   nullptr, kbuf };
            g3.e[2] = { attn_v_w + dd, attn_v_b + (size_t)l * kD, nullptr, vbuf };
            gemm32<1, 0><<<dim3(kR / 32, kD / 64, 3), 256, 0, stream>>>(
                h, g3, kR, kD, kD, 0, attn_ln_g + l * kD, attn_ln_b + l * kD);
        }
        k_scores<0><<<dim3(kMC / 64, kMC / 64, kB * kH), 256, 0, stream>>>(
            qws, kbuf, sS, nullptr, kMC, kMC, 1, 1);
        k_pv<<<dim3(kMC / 16, kB * kH), 256, 0, stream>>>(sS, vbuf, o16, kMC, kMC, 1);
        {
            GBatch g1{};
            g1.e[0] = { attn_o_w + dd, attn_o_b + (size_t)l * kD, h, h };
            gemm32<0, 0><<<dim3(kR / 32, kD / 64, 1), 256, 0, stream>>>(
                o16, g1, kR, kD, kD, 0, nullptr, nullptr);
        }

        // --- cross attention (LN fused into q staging) ---
        {
            GBatch g1{};
            g1.e[0] = { cross_q_w + dd, cross_q_b + (size_t)l * kD, nullptr, qb16 };
            gemm32<1, 1><<<dim3(kR / 32, kD / 64, 1), 256, 0, stream>>>(
                h, g1, kR, kD, kD, 0, cross_ln_g + l * kD, cross_ln_b + l * kD);
        }
        k_scores<1><<<dim3(kMC / 64, (kSA + 63) / 64, kB * kH), 256, 0, stream>>>(
            qb16, ckbuf, sS, cqk, kSA, kSLDc, 0, 0);
        k_pv<<<dim3(kMC / 16, kB * kH), 256, 0, stream>>>(sS, cvbuf, o16, kSA, kSLDc, 0);
        {
            GBatch g1{};
            g1.e[0] = { cross_o_w + dd, cross_o_b + (size_t)l * kD, h, h };
            gemm32<0, 0><<<dim3(kR / 32, kD / 64, 1), 256, 0, stream>>>(
                o16, g1, kR, kD, kD, 0, nullptr, nullptr);
        }

        // --- MLP (LN fused into w1 staging) ---
        {
            GBatch g1{};
            g1.e[0] = { mlp_w1 + (size_t)l * 4 * kD * kD, mlp_b1 + (size_t)l * 4 * kD,
                        nullptr, hid16 };
            gemm32<1, 1><<<dim3(kR / 32, 4 * kD / 64, 1), 256, 0, stream>>>(
                h, g1, kR, 4 * kD, kD, 1, mlp_ln_g + l * kD, mlp_ln_b + l * kD);
        }
        {
            GBatch g1{};
            g1.e[0] = { mlp_w2 + (size_t)l * 4 * kD * kD, mlp_b2 + (size_t)l * kD, h, h };
            gemm32<0, 0><<<dim3(kR / 32, kD / 64, 1), 256, 0, stream>>>(
                hid16, g1, kR, kD, 4 * kD, 0, nullptr, nullptr);
        }
    }

    k_finalln<<<kB * kT, 256, 0, stream>>>(h, ln_g, ln_b, yF16);
    k_logits<<<dim3((kV + 63) / 64), 256, 0, stream>>>(yF16, tok, out);
}

// Round 17
// 3063.815 us; speedup vs baseline: 1.1084x; 1.1084x over previous
//
#include <hip/hip_runtime.h>
#include <math.h>

// ---- problem constants --------------------------------------------------
constexpr int kL = 12, kD = 768, kH = 12, kV = 51865, kSA = 1500;
constexpr int kB = 2, kT = 192, kMC = 256, kDH = 64;
constexpr float kScale = 0.125f;      // DH^-0.5
constexpr float kEps = 1e-5f;
constexpr int kR = kB * kMC;          // 512 rows through the layer stack
constexpr int kSLDc = 1504;           // cross score row stride (elements)

// ---- d_out layout (flat float32, reference return order) ---------------
constexpr size_t SZ_LOGITS = (size_t)kB * kT * kV;
constexpr size_t SZ_CQK    = (size_t)kL * kB * kH * kT * kSA;
constexpr size_t SZ_MKV    = (size_t)2 * kL * kB * kMC * kD;
constexpr size_t OFF_CQK = SZ_LOGITS;
constexpr size_t OFF_MKV = OFF_CQK + SZ_CQK;
constexpr size_t OFF_CKV = OFF_MKV + SZ_MKV;

typedef float f32x4v __attribute__((ext_vector_type(4)));
typedef unsigned short us8v __attribute__((ext_vector_type(8)));
typedef unsigned short us4v __attribute__((ext_vector_type(4)));
typedef unsigned int   u32x4 __attribute__((ext_vector_type(4)));

static __device__ __forceinline__ unsigned short f2bf(float f) {
    unsigned int u = __float_as_uint(f);
    u += 0x7fffu + ((u >> 16) & 1u);          // round-to-nearest-even
    return (unsigned short)(u >> 16);
}

// packed f32x2 -> bf16x2 (RNE), low half from `lo`
static __device__ __forceinline__ unsigned int f2bf2(float lo, float hi) {
    unsigned int r;
    asm("v_cvt_pk_bf16_f32 %0, %1, %2" : "=v"(r) : "v"(lo), "v"(hi));
    return r;
}

static __device__ __forceinline__ float bf2f(unsigned short u) {
    return __uint_as_float((unsigned int)u << 16);
}

static __device__ __forceinline__ f32x4v mfma_bf16(us8v a, us8v b, f32x4v c) {
    asm("v_mfma_f32_16x16x32_bf16 %0, %1, %2, %0" : "+v"(c) : "v"(a), "v"(b));
    return c;
}

// ========================================================================
// embedding
// ========================================================================
__global__ void k_embed(const int* __restrict__ x, const float* __restrict__ tok,
                        const float* __restrict__ pos, float* __restrict__ h)
{
    int idx = blockIdx.x * 256 + threadIdx.x;
    int d = idx % kD;
    int t = (idx / kD) % kMC;
    int b = idx / (kD * kMC);
    float v = 0.f;
    if (t < kT) {
        int tokid = x[b * kT + t];
        v = tok[(size_t)tokid * kD + d] + pos[(size_t)t * kD + d];
    }
    h[idx] = v;
}

// ========================================================================
// fp32 -> bf16 bulk conversion (RNE; same rounding as in-staging cvt)
// ========================================================================
__global__ void k_cvtbf(const float* __restrict__ in,
                        unsigned short* __restrict__ out, int n8)
{
    int i = blockIdx.x * 256 + threadIdx.x;
    if (i >= n8) return;
    const float* p = in + (size_t)i * 8;
    float4 v0 = *(const float4*)(p);
    float4 v1 = *(const float4*)(p + 4);
    u32x4 q;
    q[0] = f2bf2(v0.x, v0.y); q[1] = f2bf2(v0.z, v0.w);
    q[2] = f2bf2(v1.x, v1.y); q[3] = f2bf2(v1.z, v1.w);
    *(u32x4*)&out[(size_t)i * 8] = q;
}

// ========================================================================
// LayerNorm (256 thr per row of 768) -> bf16 output
// ========================================================================
__global__ void k_ln(const float* __restrict__ in, const float* __restrict__ g,
                     const float* __restrict__ bb, unsigned short* __restrict__ out)
{
    int r = blockIdx.x;
    const float* xr = in + (size_t)r * kD;
    int t = threadIdx.x;
    float x0 = xr[t], x1 = xr[t + 256], x2 = xr[t + 512];
    float s  = x0 + x1 + x2;
    float sq = x0 * x0 + x1 * x1 + x2 * x2;
    __shared__ float red[8];
    for (int o = 32; o > 0; o >>= 1) { s += __shfl_down(s, o); sq += __shfl_down(sq, o); }
    int w = t >> 6;
    if ((t & 63) == 0) { red[w] = s; red[4 + w] = sq; }
    __syncthreads();
    s  = red[0] + red[1] + red[2] + red[3];
    sq = red[4] + red[5] + red[6] + red[7];
    float m   = s * (1.f / kD);
    float var = sq * (1.f / kD) - m * m;
    float rs  = rsqrtf(var + kEps);
    unsigned short* orow = out + (size_t)r * kD;
    orow[t]       = f2bf((x0 - m) * rs * g[t]       + bb[t]);
    orow[t + 256] = f2bf((x1 - m) * rs * g[t + 256] + bb[t + 256]);
    orow[t + 512] = f2bf((x2 - m) * rs * g[t + 512] + bb[t + 512]);
}

__global__ void k_finalln(const float* __restrict__ h, const float* __restrict__ g,
                          const float* __restrict__ bb, unsigned short* __restrict__ out)
{
    int r = blockIdx.x;                 // 0..kB*kT
    int b = r / kT, tt = r % kT;
    const float* xr = h + (size_t)(b * kMC + tt) * kD;
    int t = threadIdx.x;
    float x0 = xr[t], x1 = xr[t + 256], x2 = xr[t + 512];
    float s  = x0 + x1 + x2;
    float sq = x0 * x0 + x1 * x1 + x2 * x2;
    __shared__ float red[8];
    for (int o = 32; o > 0; o >>= 1) { s += __shfl_down(s, o); sq += __shfl_down(sq, o); }
    int w = t >> 6;
    if ((t & 63) == 0) { red[w] = s; red[4 + w] = sq; }
    __syncthreads();
    s  = red[0] + red[1] + red[2] + red[3];
    sq = red[4] + red[5] + red[6] + red[7];
    float m   = s * (1.f / kD);
    float var = sq * (1.f / kD) - m * m;
    float rs  = rsqrtf(var + kEps);
    unsigned short* orow = out + (size_t)r * kD;
    orow[t]       = f2bf((x0 - m) * rs * g[t]       + bb[t]);
    orow[t + 256] = f2bf((x1 - m) * rs * g[t + 256] + bb[t + 256]);
    orow[t + 512] = f2bf((x2 - m) * rs * g[t + 512] + bb[t + 512]);
}

// ========================================================================
// bf16-MFMA GEMM (BM=64), triple-buffered, prefetch distance 2.
// Used for the bf16-A cross-K/V init batch. (round-12 proven)
// ========================================================================
struct GEntry { const float* W; const float* bias; const float* res; void* out; };
struct GBatch { GEntry e[24]; };

template <int ABF, int OBF>
__global__ __launch_bounds__(256)
void gemm_t(const void* __restrict__ Av, GBatch gb, int M, int N, int K,
            int dogelu)
{
    constexpr int LD = 72;
    __shared__ unsigned short As[3][64][LD];
    __shared__ unsigned short Ws[3][64][LD];
    const GEntry ge = gb.e[blockIdx.z];
    const float* __restrict__ W = ge.W;
    int bn = blockIdx.y * 64;
    int bm = blockIdx.x * 64;
    int tid = threadIdx.x;
    int wid = tid >> 6, lane = tid & 63;
    int wm = (wid >> 1) * 32, wn = (wid & 1) * 32;
    int l15 = lane & 15, lg = lane >> 4;
    int r = tid >> 2, cq = (tid & 3) * 16;
    int gr = bm + r, gc = bn + r;

    auto load_a = [&](int k0, u32x4& p0, u32x4& p1) {
        p0 = (u32x4){}; p1 = (u32x4){};
        if (ABF) {
            if (gr < M) {
                const unsigned short* ar =
                    (const unsigned short*)Av + (size_t)gr * K + k0 + cq;
                p0 = *(const u32x4*)ar;
                p1 = *(const u32x4*)(ar + 8);
            }
        } else {
            if (gr < M) {
                const float* ar = (const float*)Av + (size_t)gr * K + k0 + cq;
                float4 v0 = *(const float4*)(ar);
                float4 v1 = *(const float4*)(ar + 4);
                float4 v2 = *(const float4*)(ar + 8);
                float4 v3 = *(const float4*)(ar + 12);
                p0[0] = f2bf2(v0.x, v0.y); p0[1] = f2bf2(v0.z, v0.w);
                p0[2] = f2bf2(v1.x, v1.y); p0[3] = f2bf2(v1.z, v1.w);
                p1[0] = f2bf2(v2.x, v2.y); p1[1] = f2bf2(v2.z, v2.w);
                p1[2] = f2bf2(v3.x, v3.y); p1[3] = f2bf2(v3.z, v3.w);
            }
        }
    };
    auto load_w = [&](int k0, u32x4& p0, u32x4& p1) {
        p0 = (u32x4){}; p1 = (u32x4){};
        if (gc < N) {
            const float* wr = W + (size_t)gc * K + k0 + cq;
            float4 v0 = *(const float4*)(wr);
            float4 v1 = *(const float4*)(wr + 4);
            float4 v2 = *(const float4*)(wr + 8);
            float4 v3 = *(const float4*)(wr + 12);
            p0[0] = f2bf2(v0.x, v0.y); p0[1] = f2bf2(v0.z, v0.w);
            p0[2] = f2bf2(v1.x, v1.y); p0[3] = f2bf2(v1.z, v1.w);
            p1[0] = f2bf2(v2.x, v2.y); p1[1] = f2bf2(v2.z, v2.w);
            p1[2] = f2bf2(v3.x, v3.y); p1[3] = f2bf2(v3.z, v3.w);
        }
    };
    auto stage = [&](int buf, u32x4 a0, u32x4 a1, u32x4 w0, u32x4 w1) {
        *(u32x4*)&As[buf][r][cq]     = a0;
        *(u32x4*)&As[buf][r][cq + 8] = a1;
        *(u32x4*)&Ws[buf][r][cq]     = w0;
        *(u32x4*)&Ws[buf][r][cq + 8] = w1;
    };

    f32x4v acc00 = {}, acc01 = {}, acc10 = {}, acc11 = {};
    auto domfma = [&](int buf) {
        #pragma unroll
        for (int kc = 0; kc < 2; ++kc) {
            us8v af0 = *(const us8v*)&As[buf][wm + l15][kc * 32 + lg * 8];
            us8v af1 = *(const us8v*)&As[buf][wm + 16 + l15][kc * 32 + lg * 8];
            us8v wf0 = *(const us8v*)&Ws[buf][wn + l15][kc * 32 + lg * 8];
            us8v wf1 = *(const us8v*)&Ws[buf][wn + 16 + l15][kc * 32 + lg * 8];
            acc00 = mfma_bf16(af0, wf0, acc00);
            acc01 = mfma_bf16(af0, wf1, acc01);
            acc10 = mfma_bf16(af1, wf0, acc10);
            acc11 = mfma_bf16(af1, wf1, acc11);
        }
    };

    u32x4 a0A, a1A, w0A, w1A, a0B, a1B, w0B, w1B;
    load_a(0, a0A, a1A); load_w(0, w0A, w1A);
    stage(0, a0A, a1A, w0A, w1A);
    load_a(64, a0B, a1B); load_w(64, w0B, w1B);
    __syncthreads();

    int cur = 0;
    for (int k0 = 0; k0 < K; k0 += 128) {
        int n1 = cur + 1; if (n1 == 3) n1 = 0;
        int n2 = n1 + 1; if (n2 == 3) n2 = 0;
        if (k0 + 128 < K) { load_a(k0 + 128, a0A, a1A); load_w(k0 + 128, w0A, w1A); }
        domfma(cur);
        stage(n1, a0B, a1B, w0B, w1B);
        __syncthreads();
        if (k0 + 192 < K) { load_a(k0 + 192, a0B, a1B); load_w(k0 + 192, w0B, w1B); }
        domfma(n1);
        if (k0 + 128 < K) {
            stage(n2, a0A, a1A, w0A, w1A);
            __syncthreads();
        }
        cur = n2;
    }

    const float* bias = ge.bias;
    const float* res  = ge.res;
    f32x4v accs[2][2] = { { acc00, acc01 }, { acc10, acc11 } };
    #pragma unroll
    for (int fi = 0; fi < 2; ++fi) {
        #pragma unroll
        for (int fj = 0; fj < 2; ++fj) {
            int col = bn + wn + fj * 16 + l15;
            if (col >= N) continue;
            float bv = bias ? bias[col] : 0.f;
            #pragma unroll
            for (int rr = 0; rr < 4; ++rr) {
                int row = bm + wm + fi * 16 + lg * 4 + rr;
                if (row >= M) continue;
                float v = accs[fi][fj][rr] + bv;
                if (dogelu) v = 0.5f * v * (1.f + erff(v * 0.70710678118654752f));
                if (OBF) {
                    ((unsigned short*)ge.out)[(size_t)row * N + col] = f2bf(v);
                } else {
                    if (res) v += res[(size_t)row * N + col];
                    ((float*)ge.out)[(size_t)row * N + col] = v;
                }
            }
        }
    }
}

// ========================================================================
// bf16-MFMA GEMM, BM=32/BN=64 (2x block count), triple-buffered. (rnd 15)
// ========================================================================
template <int OBF>
__global__ __launch_bounds__(256)
void gemm32(const unsigned short* __restrict__ A, GBatch gb, int M, int N, int K,
            int dogelu)
{
    constexpr int LD = 72;
    __shared__ unsigned short As[3][32][LD];
    __shared__ unsigned short Ws[3][64][LD];
    const GEntry ge = gb.e[blockIdx.z];
    const float* __restrict__ W = ge.W;
    int bn = blockIdx.y * 64;
    int bm = blockIdx.x * 32;
    int tid = threadIdx.x;
    int wid = tid >> 6, lane = tid & 63;
    int wr = (wid >> 1) * 16, wc = (wid & 1) * 32;
    int l15 = lane & 15, lg = lane >> 4;
    int ra = tid >> 3, ca = (tid & 7) * 8;    // A staging: 32 rows x 64 k
    int rw = tid >> 2, cw = (tid & 3) * 16;   // W staging: 64 rows x 64 k
    int gr = bm + ra, gc = bn + rw;

    auto load_a = [&](int k0, us8v& p) {
        p = (us8v){};
        if (gr < M) p = *(const us8v*)(A + (size_t)gr * K + k0 + ca);
    };
    auto load_w = [&](int k0, u32x4& p0, u32x4& p1) {
        p0 = (u32x4){}; p1 = (u32x4){};
        if (gc < N) {
            const float* wrp = W + (size_t)gc * K + k0 + cw;
            float4 v0 = *(const float4*)(wrp);
            float4 v1 = *(const float4*)(wrp + 4);
            float4 v2 = *(const float4*)(wrp + 8);
            float4 v3 = *(const float4*)(wrp + 12);
            p0[0] = f2bf2(v0.x, v0.y); p0[1] = f2bf2(v0.z, v0.w);
            p0[2] = f2bf2(v1.x, v1.y); p0[3] = f2bf2(v1.z, v1.w);
            p1[0] = f2bf2(v2.x, v2.y); p1[1] = f2bf2(v2.z, v2.w);
            p1[2] = f2bf2(v3.x, v3.y); p1[3] = f2bf2(v3.z, v3.w);
        }
    };
    auto stage = [&](int buf, us8v a, u32x4 w0, u32x4 w1) {
        *(us8v*)&As[buf][ra][ca]      = a;
        *(u32x4*)&Ws[buf][rw][cw]     = w0;
        *(u32x4*)&Ws[buf][rw][cw + 8] = w1;
    };

    f32x4v acc0 = {}, acc1 = {};
    auto domfma = [&](int buf) {
        #pragma unroll
        for (int kc = 0; kc < 2; ++kc) {
            us8v af  = *(const us8v*)&As[buf][wr + l15][kc * 32 + lg * 8];
            us8v wf0 = *(const us8v*)&Ws[buf][wc + l15][kc * 32 + lg * 8];
            us8v wf1 = *(const us8v*)&Ws[buf][wc + 16 + l15][kc * 32 + lg * 8];
            acc0 = mfma_bf16(af, wf0, acc0);
            acc1 = mfma_bf16(af, wf1, acc1);
        }
    };

    us8v aA, aB;
    u32x4 w0A, w1A, w0B, w1B;
    load_a(0, aA); load_w(0, w0A, w1A);
    stage(0, aA, w0A, w1A);
    load_a(64, aB); load_w(64, w0B, w1B);
    __syncthreads();

    int cur = 0;
    for (int k0 = 0; k0 < K; k0 += 128) {
        int n1 = cur + 1; if (n1 == 3) n1 = 0;
        int n2 = n1 + 1; if (n2 == 3) n2 = 0;
        if (k0 + 128 < K) { load_a(k0 + 128, aA); load_w(k0 + 128, w0A, w1A); }
        domfma(cur);
        stage(n1, aB, w0B, w1B);
        __syncthreads();
        if (k0 + 192 < K) { load_a(k0 + 192, aB); load_w(k0 + 192, w0B, w1B); }
        domfma(n1);
        if (k0 + 128 < K) {
            stage(n2, aA, w0A, w1A);
            __syncthreads();
        }
        cur = n2;
    }

    const float* bias = ge.bias;
    const float* res  = ge.res;
    f32x4v accs[2] = { acc0, acc1 };
    #pragma unroll
    for (int fj = 0; fj < 2; ++fj) {
        int col = bn + wc + fj * 16 + l15;
        if (col >= N) continue;
        float bv = bias ? bias[col] : 0.f;
        #pragma unroll
        for (int rr = 0; rr < 4; ++rr) {
            int row = bm + wr + lg * 4 + rr;
            if (row >= M) continue;
            float v = accs[fj][rr] + bv;
            if (dogelu) v = 0.5f * v * (1.f + erff(v * 0.70710678118654752f));
            if (OBF) {
                ((unsigned short*)ge.out)[(size_t)row * N + col] = f2bf(v);
            } else {
                if (res) v += res[(size_t)row * N + col];
                ((float*)ge.out)[(size_t)row * N + col] = v;
            }
        }
    }
}

// ========================================================================
// Logits GEMM: k0-outer / m-tile-inner, W AND A double-buffered
// (one barrier per phase; A for phase p+1 prefetched during phase p).
// ========================================================================
__global__ __launch_bounds__(256)
void k_logits(const unsigned short* __restrict__ A, const float* __restrict__ W,
              float* __restrict__ out)
{
    constexpr int LD = 72;
    __shared__ unsigned short As[2][64][LD];
    __shared__ unsigned short Ws[2][64][LD];
    int bn = blockIdx.x * 64;
    int tid = threadIdx.x;
    int wid = tid >> 6, lane = tid & 63;
    int wm = (wid >> 1) * 32, wn = (wid & 1) * 32;
    int l15 = lane & 15, lg = lane >> 4;
    int r = tid >> 2, cq = (tid & 3) * 16;
    int gc = bn + r;

    auto load_w = [&](int k0, u32x4& p0, u32x4& p1) {
        p0 = (u32x4){}; p1 = (u32x4){};
        if (gc < kV) {
            const float* wr = W + (size_t)gc * kD + k0 + cq;
            float4 v0 = *(const float4*)(wr);
            float4 v1 = *(const float4*)(wr + 4);
            float4 v2 = *(const float4*)(wr + 8);
            float4 v3 = *(const float4*)(wr + 12);
            p0[0] = f2bf2(v0.x, v0.y); p0[1] = f2bf2(v0.z, v0.w);
            p0[2] = f2bf2(v1.x, v1.y); p0[3] = f2bf2(v1.z, v1.w);
            p1[0] = f2bf2(v2.x, v2.y); p1[1] = f2bf2(v2.z, v2.w);
            p1[2] = f2bf2(v3.x, v3.y); p1[3] = f2bf2(v3.z, v3.w);
        }
    };
    auto load_a = [&](int k0, int mt, us8v& v0, us8v& v1) {
        const unsigned short* ar = A + (size_t)(mt * 64 + r) * kD + k0 + cq;
        v0 = *(const us8v*)ar;
        v1 = *(const us8v*)(ar + 8);
    };

    f32x4v acc[6][4];
    #pragma unroll
    for (int i = 0; i < 6; ++i)
        #pragma unroll
        for (int j = 0; j < 4; ++j) acc[i][j] = (f32x4v){};

    u32x4 rw0, rw1;
    us8v ra0, ra1;
    load_w(0, rw0, rw1);
    load_a(0, 0, ra0, ra1);
    *(u32x4*)&Ws[0][r][cq]     = rw0;
    *(u32x4*)&Ws[0][r][cq + 8] = rw1;
    *(us8v*)&As[0][r][cq]      = ra0;
    *(us8v*)&As[0][r][cq + 8]  = ra1;
    __syncthreads();

    int acur = 0, wcur = 0;
    for (int k0 = 0; k0 < kD; k0 += 64) {
        bool morek = (k0 + 64) < kD;
        if (morek) load_w(k0 + 64, rw0, rw1);
        #pragma unroll
        for (int mt = 0; mt < 6; ++mt) {
            bool last = !morek && (mt == 5);
            if (!last) {
                int nmt = (mt == 5) ? 0 : mt + 1;
                int nk0 = (mt == 5) ? k0 + 64 : k0;
                load_a(nk0, nmt, ra0, ra1);
            }
            #pragma unroll
            for (int kc = 0; kc < 2; ++kc) {
                us8v af0 = *(const us8v*)&As[acur][wm + l15][kc * 32 + lg * 8];
                us8v af1 = *(const us8v*)&As[acur][wm + 16 + l15][kc * 32 + lg * 8];
                us8v wf0 = *(const us8v*)&Ws[wcur][wn + l15][kc * 32 + lg * 8];
                us8v wf1 = *(const us8v*)&Ws[wcur][wn + 16 + l15][kc * 32 + lg * 8];
                acc[mt][0] = mfma_bf16(af0, wf0, acc[mt][0]);
                acc[mt][1] = mfma_bf16(af0, wf1, acc[mt][1]);
                acc[mt][2] = mfma_bf16(af1, wf0, acc[mt][2]);
                acc[mt][3] = mfma_bf16(af1, wf1, acc[mt][3]);
            }
            if (!last) {
                *(us8v*)&As[acur ^ 1][r][cq]     = ra0;
                *(us8v*)&As[acur ^ 1][r][cq + 8] = ra1;
                if (mt == 5) {
                    *(u32x4*)&Ws[wcur ^ 1][r][cq]     = rw0;
                    *(u32x4*)&Ws[wcur ^ 1][r][cq + 8] = rw1;
                }
                __syncthreads();
                acur ^= 1;
                if (mt == 5) wcur ^= 1;
            }
        }
    }
    #pragma unroll
    for (int mt = 0; mt < 6; ++mt) {
        #pragma unroll
        for (int fi = 0; fi < 2; ++fi) {
            #pragma unroll
            for (int fj = 0; fj < 2; ++fj) {
                int col = bn + wn + fj * 16 + l15;
                if (col >= kV) continue;
                #pragma unroll
                for (int rr = 0; rr < 4; ++rr) {
                    int row = mt * 64 + wm + fi * 16 + lg * 4 + rr;
                    out[(size_t)row * kV + col] = acc[mt][fi * 2 + fj][rr];
                }
            }
        }
    }
}

// ========================================================================
// Attention scores via MFMA -> bf16 scratch (+fp32 cqk for cross) (rnd 12)
// ========================================================================
template <int QBF>
__global__ __launch_bounds__(256)
void k_scores(const void* __restrict__ qv, const float* __restrict__ kk,
              unsigned short* __restrict__ sws, float* __restrict__ cqk,
              int Nk, int sld, int selfmask, int kPerB)
{
    constexpr int LD = 72;
    __shared__ unsigned short As[64][LD];
    __shared__ unsigned short Ks[64][LD];
    int z = blockIdx.z, b = z / kH, h = z % kH;
    int bm = blockIdx.x * 64, bn = blockIdx.y * 64;
    const float* kbase = kk + (kPerB ? (size_t)b * kMC * kD : 0) + (size_t)h * kDH;

    int tid = threadIdx.x;
    int r = tid >> 2, c0 = (tid & 3) * 16;
    {
        if (QBF) {
            const unsigned short* q = (const unsigned short*)qv;
            const unsigned short* qr =
                q + (size_t)(b * kMC + bm + r) * kD + h * kDH + c0;
            *(us8v*)&As[r][c0]     = *(const us8v*)qr;
            *(us8v*)&As[r][c0 + 8] = *(const us8v*)(qr + 8);
        } else {
            const float* q = (const float*)qv;
            const float* qr = q + (size_t)(b * kMC + bm + r) * kD + h * kDH + c0;
            float4 v0 = *(const float4*)(qr);
            float4 v1 = *(const float4*)(qr + 4);
            float4 v2 = *(const float4*)(qr + 8);
            float4 v3 = *(const float4*)(qr + 12);
            u32x4 p0, p1;
            p0[0] = f2bf2(v0.x, v0.y); p0[1] = f2bf2(v0.z, v0.w);
            p0[2] = f2bf2(v1.x, v1.y); p0[3] = f2bf2(v1.z, v1.w);
            p1[0] = f2bf2(v2.x, v2.y); p1[1] = f2bf2(v2.z, v2.w);
            p1[2] = f2bf2(v3.x, v3.y); p1[3] = f2bf2(v3.z, v3.w);
            *(u32x4*)&As[r][c0]     = p0;
            *(u32x4*)&As[r][c0 + 8] = p1;
        }
        int gk = bn + r;
        if (gk < Nk) {
            const float* kr = kbase + (size_t)gk * kD + c0;
            float4 v0 = *(const float4*)(kr);
            float4 v1 = *(const float4*)(kr + 4);
            float4 v2 = *(const float4*)(kr + 8);
            float4 v3 = *(const float4*)(kr + 12);
            u32x4 p0, p1;
            p0[0] = f2bf2(v0.x, v0.y); p0[1] = f2bf2(v0.z, v0.w);
            p0[2] = f2bf2(v1.x, v1.y); p0[3] = f2bf2(v1.z, v1.w);
            p1[0] = f2bf2(v2.x, v2.y); p1[1] = f2bf2(v2.z, v2.w);
            p1[2] = f2bf2(v3.x, v3.y); p1[3] = f2bf2(v3.z, v3.w);
            *(u32x4*)&Ks[r][c0]     = p0;
            *(u32x4*)&Ks[r][c0 + 8] = p1;
        } else {
            u32x4 zz = {};
            *(u32x4*)&Ks[r][c0]     = zz;
            *(u32x4*)&Ks[r][c0 + 8] = zz;
        }
    }
    __syncthreads();

    int wid = tid >> 6, lane = tid & 63;
    int wm = (wid >> 1) * 32, wn = (wid & 1) * 32;
    int l15 = lane & 15, lg = lane >> 4;

    f32x4v acc[2][2] = {};
    #pragma unroll
    for (int kc = 0; kc < 2; ++kc) {
        us8v a0 = *(const us8v*)&As[wm + l15][kc * 32 + lg * 8];
        us8v a1 = *(const us8v*)&As[wm + 16 + l15][kc * 32 + lg * 8];
        us8v b0 = *(const us8v*)&Ks[wn + l15][kc * 32 + lg * 8];
        us8v b1 = *(const us8v*)&Ks[wn + 16 + l15][kc * 32 + lg * 8];
        acc[0][0] = mfma_bf16(a0, b0, acc[0][0]);
        acc[0][1] = mfma_bf16(a0, b1, acc[0][1]);
        acc[1][0] = mfma_bf16(a1, b0, acc[1][0]);
        acc[1][1] = mfma_bf16(a1, b1, acc[1][1]);
    }

    #pragma unroll
    for (int fm = 0; fm < 2; ++fm) {
        #pragma unroll
        for (int fn = 0; fn < 2; ++fn) {
            int gj = bn + wn + fn * 16 + l15;
            if (gj >= Nk) continue;
            #pragma unroll
            for (int rr = 0; rr < 4; ++rr) {
                int gi = bm + wm + fm * 16 + lg * 4 + rr;
                float val = acc[fm][fn][rr] * kScale;
                if (cqk && gi < kT)
                    cqk[(((size_t)(b * kH + h)) * kT + gi) * kSA + gj] = val;
                if (selfmask && (gj > gi || gj >= kT)) val = -1e30f;
                sws[((size_t)z * kMC + gi) * sld + gj] = f2bf(val);
            }
        }
    }
}

// ========================================================================
// Softmax + PV via MFMA, bf16 scores. Block = 16 q-rows of one z (rnd 12).
// ========================================================================
constexpr int kCH  = 128;   // key chunk
constexpr int kLDK = 136;   // bf16 k-stride
__global__ __launch_bounds__(256)
void k_pv(const unsigned short* __restrict__ sws, const float* __restrict__ vv,
          unsigned short* __restrict__ o, int Nk, int sld, int vPerB)
{
    __shared__ unsigned short Pb[16][kLDK];
    __shared__ unsigned short Vt[64][kLDK];
    __shared__ float smx[16], sinv[16];
    int z = blockIdx.y, b = z / kH, h = z % kH;
    int i0 = blockIdx.x * 16;
    int t = threadIdx.x, wid = t >> 6, lane = t & 63;
    int l15 = lane & 15, lg = lane >> 4;
    const float* vbase = vv + (vPerB ? (size_t)b * kMC * kD : 0) + (size_t)h * kDH;

    // ---- pass 1: row max & inv-sum (vectorized 8-wide reads) ----
    for (int r2 = wid; r2 < 16; r2 += 4) {
        const unsigned short* srow2 = sws + ((size_t)z * kMC + i0 + r2) * sld;
        float mx = -3e38f;
        for (int j0 = lane * 8; j0 < Nk; j0 += 512) {
            us8v v = *(const us8v*)&srow2[j0];
            #pragma unroll
            for (int e = 0; e < 8; ++e)
                if (j0 + e < Nk) mx = fmaxf(mx, bf2f(v[e]));
        }
        for (int off = 32; off > 0; off >>= 1) mx = fmaxf(mx, __shfl_xor(mx, off));
        float sum = 0.f;
        for (int j0 = lane * 8; j0 < Nk; j0 += 512) {
            us8v v = *(const us8v*)&srow2[j0];
            #pragma unroll
            for (int e = 0; e < 8; ++e)
                if (j0 + e < Nk) sum += expf(bf2f(v[e]) - mx);
        }
        for (int off = 32; off > 0; off >>= 1) sum += __shfl_xor(sum, off);
        if (lane == 0) { smx[r2] = mx; sinv[r2] = 1.f / sum; }
    }
    __syncthreads();

    // ---- pass 2: chunked MFMA PV ----
    int pr = t >> 4;                 // P-stage row 0..15
    int jb = (t & 15) * 8;           // P-stage key base within chunk
    const unsigned short* srow = sws + ((size_t)z * kMC + i0 + pr) * sld;
    float mxv = smx[pr];

    f32x4v acc = {};
    for (int k0 = 0; k0 < Nk; k0 += kCH) {
        #pragma unroll
        for (int u = 0; u < 4; ++u) {
            int flat = t + u * 256;
            int kr = (flat >> 4) * 2;
            int c4 = flat & 15;
            float4 va = {0,0,0,0}, vb2 = {0,0,0,0};
            if (k0 + kr < Nk)
                va = *(const float4*)(vbase + (size_t)(k0 + kr) * kD + c4 * 4);
            if (k0 + kr + 1 < Nk)
                vb2 = *(const float4*)(vbase + (size_t)(k0 + kr + 1) * kD + c4 * 4);
            *(unsigned int*)&Vt[c4 * 4 + 0][kr] = f2bf2(va.x, vb2.x);
            *(unsigned int*)&Vt[c4 * 4 + 1][kr] = f2bf2(va.y, vb2.y);
            *(unsigned int*)&Vt[c4 * 4 + 2][kr] = f2bf2(va.z, vb2.z);
            *(unsigned int*)&Vt[c4 * 4 + 3][kr] = f2bf2(va.w, vb2.w);
        }
        {
            us8v praw = *(const us8v*)&srow[k0 + jb];
            #pragma unroll
            for (int u = 0; u < 8; u += 2) {
                int gj0 = k0 + jb + u;
                float e0 = (gj0     < Nk) ? expf(bf2f(praw[u])     - mxv) : 0.f;
                float e1 = (gj0 + 1 < Nk) ? expf(bf2f(praw[u + 1]) - mxv) : 0.f;
                *(unsigned int*)&Pb[pr][jb + u] = f2bf2(e0, e1);
            }
        }
        __syncthreads();
        #pragma unroll
        for (int kc = 0; kc < 4; ++kc) {
            us8v a  = *(const us8v*)&Pb[l15][kc * 32 + lg * 8];
            us8v bf = *(const us8v*)&Vt[wid * 16 + l15][kc * 32 + lg * 8];
            acc = mfma_bf16(a, bf, acc);
        }
        __syncthreads();
    }

    #pragma unroll
    for (int rr = 0; rr < 4; ++rr) {
        int row = lg * 4 + rr;
        float v = acc[rr] * sinv[row];
        o[(size_t)(b * kMC + i0 + row) * kD + h * kDH + wid * 16 + l15] = f2bf(v);
    }
}

// ========================================================================
extern "C" void kernel_launch(void* const* d_in, const int* in_sizes, int n_in,
                              void* d_out, int out_size, void* d_ws, size_t ws_size,
                              hipStream_t stream)
{
    const int*   x   = (const int*)  d_in[0];
    const float* xa  = (const float*)d_in[1];
    const float* tok = (const float*)d_in[4];
    const float* pos = (const float*)d_in[5];
    const float* attn_ln_g  = (const float*)d_in[6];
    const float* attn_ln_b  = (const float*)d_in[7];
    const float* attn_q_w   = (const float*)d_in[8];
    const float* attn_q_b   = (const float*)d_in[9];
    const float* attn_k_w   = (const float*)d_in[10];
    const float* attn_v_w   = (const float*)d_in[11];
    const float* attn_v_b   = (const float*)d_in[12];
    const float* attn_o_w   = (const float*)d_in[13];
    const float* attn_o_b   = (const float*)d_in[14];
    const float* cross_ln_g = (const float*)d_in[15];
    const float* cross_ln_b = (const float*)d_in[16];
    const float* cross_q_w  = (const float*)d_in[17];
    const float* cross_q_b  = (const float*)d_in[18];
    const float* cross_k_w  = (const float*)d_in[19];
    const float* cross_v_w  = (const float*)d_in[20];
    const float* cross_v_b  = (const float*)d_in[21];
    const float* cross_o_w  = (const float*)d_in[22];
    const float* cross_o_b  = (const float*)d_in[23];
    const float* mlp_ln_g   = (const float*)d_in[24];
    const float* mlp_ln_b   = (const float*)d_in[25];
    const float* mlp_w1     = (const float*)d_in[26];
    const float* mlp_b1     = (const float*)d_in[27];
    const float* mlp_w2     = (const float*)d_in[28];
    const float* mlp_b2     = (const float*)d_in[29];
    const float* ln_g       = (const float*)d_in[30];
    const float* ln_b       = (const float*)d_in[31];

    float* out = (float*)d_out;
    float* h    = (float*)d_ws;                          // 512*768 f32
    float* qws  = h   + (size_t)kR * kD;                 // 512*768 f32 (self q)
    unsigned short* sS    = (unsigned short*)(qws + (size_t)kR * kD); // bf16 scores
    unsigned short* y16   = sS   + (size_t)kB * kH * kMC * kSLDc;
    unsigned short* qb16  = y16  + (size_t)kR * kD;      // cross q bf16
    unsigned short* o16   = qb16 + (size_t)kR * kD;      // attn out bf16
    unsigned short* hid16 = o16  + (size_t)kR * kD;      // MLP hidden bf16
    unsigned short* yF16  = hid16 + (size_t)kR * 4 * kD; // final LN bf16
    unsigned short* xa16  = yF16 + (size_t)kB * kT * kD; // xa bf16 (1500*768)

    k_embed<<<kB * kMC * kD / 256, 256, 0, stream>>>(x, tok, pos, h);
    k_cvtbf<<<(kSA * kD / 8 + 255) / 256, 256, 0, stream>>>(xa, xa16, kSA * kD / 8);

    // all cross K/V projections (layer-invariant input xa, pre-cvt bf16)
    {
        GBatch gc{};
        for (int l = 0; l < kL; ++l) {
            gc.e[2 * l]     = { cross_k_w + (size_t)l * kD * kD, nullptr, nullptr,
                                out + OFF_CKV + (size_t)(2 * l) * kSA * kD };
            gc.e[2 * l + 1] = { cross_v_w + (size_t)l * kD * kD, cross_v_b + (size_t)l * kD,
                                nullptr,
                                out + OFF_CKV + (size_t)(2 * l + 1) * kSA * kD };
        }
        gemm_t<1, 0><<<dim3((kSA + 63) / 64, kD / 64, 2 * kL), 256, 0, stream>>>(
            xa16, gc, kSA, kD, kD, 0);
    }

    for (int l = 0; l < kL; ++l) {
        size_t dd = (size_t)l * kD * kD;
        float* kbuf  = out + OFF_MKV + (size_t)(2 * l)     * kB * kMC * kD;
        float* vbuf  = out + OFF_MKV + (size_t)(2 * l + 1) * kB * kMC * kD;
        float* ckbuf = out + OFF_CKV + (size_t)(2 * l)     * kSA * kD;
        float* cvbuf = out + OFF_CKV + (size_t)(2 * l + 1) * kSA * kD;
        float* cqk   = out + OFF_CQK + (size_t)l * kB * kH * kT * kSA;

        // --- self attention ---
        k_ln<<<kR, 256, 0, stream>>>(h, attn_ln_g + l * kD, attn_ln_b + l * kD, y16);
        {
            GBatch g3{};
            g3.e[0] = { attn_q_w + dd, attn_q_b + (size_t)l * kD, nullptr, qws };
            g3.e[1] = { attn_k_w + dd, nullptr,                   nullptr, kbuf };
            g3.e[2] = { attn_v_w + dd, attn_v_b + (size_t)l * kD, nullptr, vbuf };
            gemm32<0><<<dim3(kR / 32, kD / 64, 3), 256, 0, stream>>>(
                y16, g3, kR, kD, kD, 0);
        }
        k_scores<0><<<dim3(kMC / 64, kMC / 64, kB * kH), 256, 0, stream>>>(
            qws, kbuf, sS, nullptr, kMC, kMC, 1, 1);
        k_pv<<<dim3(kMC / 16, kB * kH), 256, 0, stream>>>(sS, vbuf, o16, kMC, kMC, 1);
        {
            GBatch g1{};
            g1.e[0] = { attn_o_w + dd, attn_o_b + (size_t)l * kD, h, h };
            gemm32<0><<<dim3(kR / 32, kD / 64, 1), 256, 0, stream>>>(
                o16, g1, kR, kD, kD, 0);
        }

        // --- cross attention ---
        k_ln<<<kR, 256, 0, stream>>>(h, cross_ln_g + l * kD, cross_ln_b + l * kD, y16);
        {
            GBatch g1{};
            g1.e[0] = { cross_q_w + dd, cross_q_b + (size_t)l * kD, nullptr, qb16 };
            gemm32<1><<<dim3(kR / 32, kD / 64, 1), 256, 0, stream>>>(
                y16, g1, kR, kD, kD, 0);
        }
        k_scores<1><<<dim3(kMC / 64, (kSA + 63) / 64, kB * kH), 256, 0, stream>>>(
            qb16, ckbuf, sS, cqk, kSA, kSLDc, 0, 0);
        k_pv<<<dim3(kMC / 16, kB * kH), 256, 0, stream>>>(sS, cvbuf, o16, kSA, kSLDc, 0);
        {
            GBatch g1{};
            g1.e[0] = { cross_o_w + dd, cross_o_b + (size_t)l * kD, h, h };
            gemm32<0><<<dim3(kR / 32, kD / 64, 1), 256, 0, stream>>>(
                o16, g1, kR, kD, kD, 0);
        }

        // --- MLP ---
        k_ln<<<kR, 256, 0, stream>>>(h, mlp_ln_g + l * kD, mlp_ln_b + l * kD, y16);
        {
            GBatch g1{};
            g1.e[0] = { mlp_w1 + (size_t)l * 4 * kD * kD, mlp_b1 + (size_t)l * 4 * kD,
                        nullptr, hid16 };
            gemm32<1><<<dim3(kR / 32, 4 * kD / 64, 1), 256, 0, stream>>>(
                y16, g1, kR, 4 * kD, kD, 1);
        }
        {
            GBatch g1{};
            g1.e[0] = { mlp_w2 + (size_t)l * 4 * kD * kD, mlp_b2 + (size_t)l * kD, h, h };
            gemm32<0><<<dim3(kR / 32, kD / 64, 1), 256, 0, stream>>>(
                hid16, g1, kR, kD, 4 * kD, 0);
        }
    }

    k_finalln<<<kB * kT, 256, 0, stream>>>(h, ln_g, ln_b, yF16);
    k_logits<<<dim3((kV + 63) / 64), 256, 0, stream>>>(yF16, tok, out);
}

// Round 18
// 2854.777 us; speedup vs baseline: 1.1896x; 1.0732x over previous
//
#include <hip/hip_runtime.h>
#include <math.h>

// ---- problem constants --------------------------------------------------
constexpr int kL = 12, kD = 768, kH = 12, kV = 51865, kSA = 1500;
constexpr int kB = 2, kT = 192, kMC = 256, kDH = 64;
constexpr float kScale = 0.125f;      // DH^-0.5
constexpr float kEps = 1e-5f;
constexpr int kR = kB * kMC;          // 512 rows through the layer stack
constexpr int kSLDc = 1504;           // cross score row stride (elements)

// ---- d_out layout (flat float32, reference return order) ---------------
constexpr size_t SZ_LOGITS = (size_t)kB * kT * kV;
constexpr size_t SZ_CQK    = (size_t)kL * kB * kH * kT * kSA;
constexpr size_t SZ_MKV    = (size_t)2 * kL * kB * kMC * kD;
constexpr size_t OFF_CQK = SZ_LOGITS;
constexpr size_t OFF_MKV = OFF_CQK + SZ_CQK;
constexpr size_t OFF_CKV = OFF_MKV + SZ_MKV;

typedef float f32x4v __attribute__((ext_vector_type(4)));
typedef unsigned short us8v __attribute__((ext_vector_type(8)));
typedef unsigned short us4v __attribute__((ext_vector_type(4)));
typedef unsigned int   u32x4 __attribute__((ext_vector_type(4)));

static __device__ __forceinline__ unsigned short f2bf(float f) {
    unsigned int u = __float_as_uint(f);
    u += 0x7fffu + ((u >> 16) & 1u);          // round-to-nearest-even
    return (unsigned short)(u >> 16);
}

// packed f32x2 -> bf16x2 (RNE), low half from `lo`
static __device__ __forceinline__ unsigned int f2bf2(float lo, float hi) {
    unsigned int r;
    asm("v_cvt_pk_bf16_f32 %0, %1, %2" : "=v"(r) : "v"(lo), "v"(hi));
    return r;
}

static __device__ __forceinline__ float bf2f(unsigned short u) {
    return __uint_as_float((unsigned int)u << 16);
}

static __device__ __forceinline__ f32x4v mfma_bf16(us8v a, us8v b, f32x4v c) {
    asm("v_mfma_f32_16x16x32_bf16 %0, %1, %2, %0" : "+v"(c) : "v"(a), "v"(b));
    return c;
}

// ========================================================================
// embedding
// ========================================================================
__global__ void k_embed(const int* __restrict__ x, const float* __restrict__ tok,
                        const float* __restrict__ pos, float* __restrict__ h)
{
    int idx = blockIdx.x * 256 + threadIdx.x;
    int d = idx % kD;
    int t = (idx / kD) % kMC;
    int b = idx / (kD * kMC);
    float v = 0.f;
    if (t < kT) {
        int tokid = x[b * kT + t];
        v = tok[(size_t)tokid * kD + d] + pos[(size_t)t * kD + d];
    }
    h[idx] = v;
}

// ========================================================================
// fp32 -> bf16 bulk conversion (RNE)
// ========================================================================
__global__ void k_cvtbf(const float* __restrict__ in,
                        unsigned short* __restrict__ out, int n8)
{
    int i = blockIdx.x * 256 + threadIdx.x;
    if (i >= n8) return;
    const float* p = in + (size_t)i * 8;
    float4 v0 = *(const float4*)(p);
    float4 v1 = *(const float4*)(p + 4);
    u32x4 q;
    q[0] = f2bf2(v0.x, v0.y); q[1] = f2bf2(v0.z, v0.w);
    q[2] = f2bf2(v1.x, v1.y); q[3] = f2bf2(v1.z, v1.w);
    *(u32x4*)&out[(size_t)i * 8] = q;
}

// ========================================================================
// LayerNorm (256 thr per row of 768) -> bf16 output
// ========================================================================
__global__ void k_ln(const float* __restrict__ in, const float* __restrict__ g,
                     const float* __restrict__ bb, unsigned short* __restrict__ out)
{
    int r = blockIdx.x;
    const float* xr = in + (size_t)r * kD;
    int t = threadIdx.x;
    float x0 = xr[t], x1 = xr[t + 256], x2 = xr[t + 512];
    float s  = x0 + x1 + x2;
    float sq = x0 * x0 + x1 * x1 + x2 * x2;
    __shared__ float red[8];
    for (int o = 32; o > 0; o >>= 1) { s += __shfl_down(s, o); sq += __shfl_down(sq, o); }
    int w = t >> 6;
    if ((t & 63) == 0) { red[w] = s; red[4 + w] = sq; }
    __syncthreads();
    s  = red[0] + red[1] + red[2] + red[3];
    sq = red[4] + red[5] + red[6] + red[7];
    float m   = s * (1.f / kD);
    float var = sq * (1.f / kD) - m * m;
    float rs  = rsqrtf(var + kEps);
    unsigned short* orow = out + (size_t)r * kD;
    orow[t]       = f2bf((x0 - m) * rs * g[t]       + bb[t]);
    orow[t + 256] = f2bf((x1 - m) * rs * g[t + 256] + bb[t + 256]);
    orow[t + 512] = f2bf((x2 - m) * rs * g[t + 512] + bb[t + 512]);
}

__global__ void k_finalln(const float* __restrict__ h, const float* __restrict__ g,
                          const float* __restrict__ bb, unsigned short* __restrict__ out)
{
    int r = blockIdx.x;                 // 0..kB*kT
    int b = r / kT, tt = r % kT;
    const float* xr = h + (size_t)(b * kMC + tt) * kD;
    int t = threadIdx.x;
    float x0 = xr[t], x1 = xr[t + 256], x2 = xr[t + 512];
    float s  = x0 + x1 + x2;
    float sq = x0 * x0 + x1 * x1 + x2 * x2;
    __shared__ float red[8];
    for (int o = 32; o > 0; o >>= 1) { s += __shfl_down(s, o); sq += __shfl_down(sq, o); }
    int w = t >> 6;
    if ((t & 63) == 0) { red[w] = s; red[4 + w] = sq; }
    __syncthreads();
    s  = red[0] + red[1] + red[2] + red[3];
    sq = red[4] + red[5] + red[6] + red[7];
    float m   = s * (1.f / kD);
    float var = sq * (1.f / kD) - m * m;
    float rs  = rsqrtf(var + kEps);
    unsigned short* orow = out + (size_t)r * kD;
    orow[t]       = f2bf((x0 - m) * rs * g[t]       + bb[t]);
    orow[t + 256] = f2bf((x1 - m) * rs * g[t + 256] + bb[t + 256]);
    orow[t + 512] = f2bf((x2 - m) * rs * g[t + 512] + bb[t + 512]);
}

// ========================================================================
// bf16-MFMA GEMM (BM=64), triple-buffered, prefetch distance 2.
// Used for the bf16-A cross-K/V init batch.
// ========================================================================
struct GEntry { const float* W; const float* bias; const float* res; void* out; };
struct GBatch { GEntry e[24]; };

template <int ABF, int OBF>
__global__ __launch_bounds__(256)
void gemm_t(const void* __restrict__ Av, GBatch gb, int M, int N, int K,
            int dogelu)
{
    constexpr int LD = 72;
    __shared__ unsigned short As[3][64][LD];
    __shared__ unsigned short Ws[3][64][LD];
    const GEntry ge = gb.e[blockIdx.z];
    const float* __restrict__ W = ge.W;
    int bn = blockIdx.y * 64;
    int bm = blockIdx.x * 64;
    int tid = threadIdx.x;
    int wid = tid >> 6, lane = tid & 63;
    int wm = (wid >> 1) * 32, wn = (wid & 1) * 32;
    int l15 = lane & 15, lg = lane >> 4;
    int r = tid >> 2, cq = (tid & 3) * 16;
    int gr = bm + r, gc = bn + r;

    auto load_a = [&](int k0, u32x4& p0, u32x4& p1) {
        p0 = (u32x4){}; p1 = (u32x4){};
        if (ABF) {
            if (gr < M) {
                const unsigned short* ar =
                    (const unsigned short*)Av + (size_t)gr * K + k0 + cq;
                p0 = *(const u32x4*)ar;
                p1 = *(const u32x4*)(ar + 8);
            }
        } else {
            if (gr < M) {
                const float* ar = (const float*)Av + (size_t)gr * K + k0 + cq;
                float4 v0 = *(const float4*)(ar);
                float4 v1 = *(const float4*)(ar + 4);
                float4 v2 = *(const float4*)(ar + 8);
                float4 v3 = *(const float4*)(ar + 12);
                p0[0] = f2bf2(v0.x, v0.y); p0[1] = f2bf2(v0.z, v0.w);
                p0[2] = f2bf2(v1.x, v1.y); p0[3] = f2bf2(v1.z, v1.w);
                p1[0] = f2bf2(v2.x, v2.y); p1[1] = f2bf2(v2.z, v2.w);
                p1[2] = f2bf2(v3.x, v3.y); p1[3] = f2bf2(v3.z, v3.w);
            }
        }
    };
    auto load_w = [&](int k0, u32x4& p0, u32x4& p1) {
        p0 = (u32x4){}; p1 = (u32x4){};
        if (gc < N) {
            const float* wr = W + (size_t)gc * K + k0 + cq;
            float4 v0 = *(const float4*)(wr);
            float4 v1 = *(const float4*)(wr + 4);
            float4 v2 = *(const float4*)(wr + 8);
            float4 v3 = *(const float4*)(wr + 12);
            p0[0] = f2bf2(v0.x, v0.y); p0[1] = f2bf2(v0.z, v0.w);
            p0[2] = f2bf2(v1.x, v1.y); p0[3] = f2bf2(v1.z, v1.w);
            p1[0] = f2bf2(v2.x, v2.y); p1[1] = f2bf2(v2.z, v2.w);
            p1[2] = f2bf2(v3.x, v3.y); p1[3] = f2bf2(v3.z, v3.w);
        }
    };
    auto stage = [&](int buf, u32x4 a0, u32x4 a1, u32x4 w0, u32x4 w1) {
        *(u32x4*)&As[buf][r][cq]     = a0;
        *(u32x4*)&As[buf][r][cq + 8] = a1;
        *(u32x4*)&Ws[buf][r][cq]     = w0;
        *(u32x4*)&Ws[buf][r][cq + 8] = w1;
    };

    f32x4v acc00 = {}, acc01 = {}, acc10 = {}, acc11 = {};
    auto domfma = [&](int buf) {
        #pragma unroll
        for (int kc = 0; kc < 2; ++kc) {
            us8v af0 = *(const us8v*)&As[buf][wm + l15][kc * 32 + lg * 8];
            us8v af1 = *(const us8v*)&As[buf][wm + 16 + l15][kc * 32 + lg * 8];
            us8v wf0 = *(const us8v*)&Ws[buf][wn + l15][kc * 32 + lg * 8];
            us8v wf1 = *(const us8v*)&Ws[buf][wn + 16 + l15][kc * 32 + lg * 8];
            acc00 = mfma_bf16(af0, wf0, acc00);
            acc01 = mfma_bf16(af0, wf1, acc01);
            acc10 = mfma_bf16(af1, wf0, acc10);
            acc11 = mfma_bf16(af1, wf1, acc11);
        }
    };

    u32x4 a0A, a1A, w0A, w1A, a0B, a1B, w0B, w1B;
    load_a(0, a0A, a1A); load_w(0, w0A, w1A);
    stage(0, a0A, a1A, w0A, w1A);
    load_a(64, a0B, a1B); load_w(64, w0B, w1B);
    __syncthreads();

    int cur = 0;
    for (int k0 = 0; k0 < K; k0 += 128) {
        int n1 = cur + 1; if (n1 == 3) n1 = 0;
        int n2 = n1 + 1; if (n2 == 3) n2 = 0;
        if (k0 + 128 < K) { load_a(k0 + 128, a0A, a1A); load_w(k0 + 128, w0A, w1A); }
        domfma(cur);
        stage(n1, a0B, a1B, w0B, w1B);
        __syncthreads();
        if (k0 + 192 < K) { load_a(k0 + 192, a0B, a1B); load_w(k0 + 192, w0B, w1B); }
        domfma(n1);
        if (k0 + 128 < K) {
            stage(n2, a0A, a1A, w0A, w1A);
            __syncthreads();
        }
        cur = n2;
    }

    const float* bias = ge.bias;
    const float* res  = ge.res;
    f32x4v accs[2][2] = { { acc00, acc01 }, { acc10, acc11 } };
    #pragma unroll
    for (int fi = 0; fi < 2; ++fi) {
        #pragma unroll
        for (int fj = 0; fj < 2; ++fj) {
            int col = bn + wn + fj * 16 + l15;
            if (col >= N) continue;
            float bv = bias ? bias[col] : 0.f;
            #pragma unroll
            for (int rr = 0; rr < 4; ++rr) {
                int row = bm + wm + fi * 16 + lg * 4 + rr;
                if (row >= M) continue;
                float v = accs[fi][fj][rr] + bv;
                if (dogelu) v = 0.5f * v * (1.f + erff(v * 0.70710678118654752f));
                if (OBF) {
                    ((unsigned short*)ge.out)[(size_t)row * N + col] = f2bf(v);
                } else {
                    if (res) v += res[(size_t)row * N + col];
                    ((float*)ge.out)[(size_t)row * N + col] = v;
                }
            }
        }
    }
}

// ========================================================================
// bf16-MFMA GEMM, BM=32/BN=64 (2x block count), triple-buffered.
// ========================================================================
template <int OBF>
__global__ __launch_bounds__(256)
void gemm32(const unsigned short* __restrict__ A, GBatch gb, int M, int N, int K,
            int dogelu)
{
    constexpr int LD = 72;
    __shared__ unsigned short As[3][32][LD];
    __shared__ unsigned short Ws[3][64][LD];
    const GEntry ge = gb.e[blockIdx.z];
    const float* __restrict__ W = ge.W;
    int bn = blockIdx.y * 64;
    int bm = blockIdx.x * 32;
    int tid = threadIdx.x;
    int wid = tid >> 6, lane = tid & 63;
    int wr = (wid >> 1) * 16, wc = (wid & 1) * 32;
    int l15 = lane & 15, lg = lane >> 4;
    int ra = tid >> 3, ca = (tid & 7) * 8;    // A staging: 32 rows x 64 k
    int rw = tid >> 2, cw = (tid & 3) * 16;   // W staging: 64 rows x 64 k
    int gr = bm + ra, gc = bn + rw;

    auto load_a = [&](int k0, us8v& p) {
        p = (us8v){};
        if (gr < M) p = *(const us8v*)(A + (size_t)gr * K + k0 + ca);
    };
    auto load_w = [&](int k0, u32x4& p0, u32x4& p1) {
        p0 = (u32x4){}; p1 = (u32x4){};
        if (gc < N) {
            const float* wrp = W + (size_t)gc * K + k0 + cw;
            float4 v0 = *(const float4*)(wrp);
            float4 v1 = *(const float4*)(wrp + 4);
            float4 v2 = *(const float4*)(wrp + 8);
            float4 v3 = *(const float4*)(wrp + 12);
            p0[0] = f2bf2(v0.x, v0.y); p0[1] = f2bf2(v0.z, v0.w);
            p0[2] = f2bf2(v1.x, v1.y); p0[3] = f2bf2(v1.z, v1.w);
            p1[0] = f2bf2(v2.x, v2.y); p1[1] = f2bf2(v2.z, v2.w);
            p1[2] = f2bf2(v3.x, v3.y); p1[3] = f2bf2(v3.z, v3.w);
        }
    };
    auto stage = [&](int buf, us8v a, u32x4 w0, u32x4 w1) {
        *(us8v*)&As[buf][ra][ca]      = a;
        *(u32x4*)&Ws[buf][rw][cw]     = w0;
        *(u32x4*)&Ws[buf][rw][cw + 8] = w1;
    };

    f32x4v acc0 = {}, acc1 = {};
    auto domfma = [&](int buf) {
        #pragma unroll
        for (int kc = 0; kc < 2; ++kc) {
            us8v af  = *(const us8v*)&As[buf][wr + l15][kc * 32 + lg * 8];
            us8v wf0 = *(const us8v*)&Ws[buf][wc + l15][kc * 32 + lg * 8];
            us8v wf1 = *(const us8v*)&Ws[buf][wc + 16 + l15][kc * 32 + lg * 8];
            acc0 = mfma_bf16(af, wf0, acc0);
            acc1 = mfma_bf16(af, wf1, acc1);
        }
    };

    us8v aA, aB;
    u32x4 w0A, w1A, w0B, w1B;
    load_a(0, aA); load_w(0, w0A, w1A);
    stage(0, aA, w0A, w1A);
    load_a(64, aB); load_w(64, w0B, w1B);
    __syncthreads();

    int cur = 0;
    for (int k0 = 0; k0 < K; k0 += 128) {
        int n1 = cur + 1; if (n1 == 3) n1 = 0;
        int n2 = n1 + 1; if (n2 == 3) n2 = 0;
        if (k0 + 128 < K) { load_a(k0 + 128, aA); load_w(k0 + 128, w0A, w1A); }
        domfma(cur);
        stage(n1, aB, w0B, w1B);
        __syncthreads();
        if (k0 + 192 < K) { load_a(k0 + 192, aB); load_w(k0 + 192, w0B, w1B); }
        domfma(n1);
        if (k0 + 128 < K) {
            stage(n2, aA, w0A, w1A);
            __syncthreads();
        }
        cur = n2;
    }

    const float* bias = ge.bias;
    const float* res  = ge.res;
    f32x4v accs[2] = { acc0, acc1 };
    #pragma unroll
    for (int fj = 0; fj < 2; ++fj) {
        int col = bn + wc + fj * 16 + l15;
        if (col >= N) continue;
        float bv = bias ? bias[col] : 0.f;
        #pragma unroll
        for (int rr = 0; rr < 4; ++rr) {
            int row = bm + wr + lg * 4 + rr;
            if (row >= M) continue;
            float v = accs[fj][rr] + bv;
            if (dogelu) v = 0.5f * v * (1.f + erff(v * 0.70710678118654752f));
            if (OBF) {
                ((unsigned short*)ge.out)[(size_t)row * N + col] = f2bf(v);
            } else {
                if (res) v += res[(size_t)row * N + col];
                ((float*)ge.out)[(size_t)row * N + col] = v;
            }
        }
    }
}

// ========================================================================
// bf16-MFMA GEMM, BM=32/BN=32 (4x block count vs BM=64/BN=64) for the
// 192-block launches (cross-q, o-proj, w2). Wave wid owns 16x16 sub-tile
// (wid>>1, wid&1). Same k-order / fragments -> bit-identical.
// ========================================================================
template <int OBF>
__global__ __launch_bounds__(256)
void gemm3232(const unsigned short* __restrict__ A, GBatch gb, int M, int N, int K,
              int dogelu)
{
    constexpr int LD = 72;
    __shared__ unsigned short As[3][32][LD];
    __shared__ unsigned short Ws[3][32][LD];
    const GEntry ge = gb.e[blockIdx.z];
    const float* __restrict__ W = ge.W;
    int bn = blockIdx.y * 32;
    int bm = blockIdx.x * 32;
    int tid = threadIdx.x;
    int wid = tid >> 6, lane = tid & 63;
    int wr = (wid >> 1) * 16, wc = (wid & 1) * 16;
    int l15 = lane & 15, lg = lane >> 4;
    int ra = tid >> 3, ca = (tid & 7) * 8;    // A staging: 32 rows x 64 k
    int gr = bm + ra, gc = bn + ra;

    auto load_a = [&](int k0, us8v& p) {
        p = (us8v){};
        if (gr < M) p = *(const us8v*)(A + (size_t)gr * K + k0 + ca);
    };
    auto load_w = [&](int k0, u32x4& p) {
        p = (u32x4){};
        if (gc < N) {
            const float* wrp = W + (size_t)gc * K + k0 + ca;
            float4 v0 = *(const float4*)(wrp);
            float4 v1 = *(const float4*)(wrp + 4);
            p[0] = f2bf2(v0.x, v0.y); p[1] = f2bf2(v0.z, v0.w);
            p[2] = f2bf2(v1.x, v1.y); p[3] = f2bf2(v1.z, v1.w);
        }
    };
    auto stage = [&](int buf, us8v a, u32x4 w) {
        *(us8v*)&As[buf][ra][ca]  = a;
        *(u32x4*)&Ws[buf][ra][ca] = w;
    };

    f32x4v acc = {};
    auto domfma = [&](int buf) {
        #pragma unroll
        for (int kc = 0; kc < 2; ++kc) {
            us8v af = *(const us8v*)&As[buf][wr + l15][kc * 32 + lg * 8];
            us8v wf = *(const us8v*)&Ws[buf][wc + l15][kc * 32 + lg * 8];
            acc = mfma_bf16(af, wf, acc);
        }
    };

    us8v aA, aB;
    u32x4 wA, wB;
    load_a(0, aA); load_w(0, wA);
    stage(0, aA, wA);
    load_a(64, aB); load_w(64, wB);
    __syncthreads();

    int cur = 0;
    for (int k0 = 0; k0 < K; k0 += 128) {
        int n1 = cur + 1; if (n1 == 3) n1 = 0;
        int n2 = n1 + 1; if (n2 == 3) n2 = 0;
        if (k0 + 128 < K) { load_a(k0 + 128, aA); load_w(k0 + 128, wA); }
        domfma(cur);
        stage(n1, aB, wB);
        __syncthreads();
        if (k0 + 192 < K) { load_a(k0 + 192, aB); load_w(k0 + 192, wB); }
        domfma(n1);
        if (k0 + 128 < K) {
            stage(n2, aA, wA);
            __syncthreads();
        }
        cur = n2;
    }

    const float* bias = ge.bias;
    const float* res  = ge.res;
    {
        int col = bn + wc + l15;
        if (col < N) {
            float bv = bias ? bias[col] : 0.f;
            #pragma unroll
            for (int rr = 0; rr < 4; ++rr) {
                int row = bm + wr + lg * 4 + rr;
                if (row >= M) continue;
                float v = acc[rr] + bv;
                if (dogelu) v = 0.5f * v * (1.f + erff(v * 0.70710678118654752f));
                if (OBF) {
                    ((unsigned short*)ge.out)[(size_t)row * N + col] = f2bf(v);
                } else {
                    if (res) v += res[(size_t)row * N + col];
                    ((float*)ge.out)[(size_t)row * N + col] = v;
                }
            }
        }
    }
}

// ========================================================================
// Logits GEMM: k0-outer / m-tile-inner, W AND A double-buffered.
// ========================================================================
__global__ __launch_bounds__(256)
void k_logits(const unsigned short* __restrict__ A, const float* __restrict__ W,
              float* __restrict__ out)
{
    constexpr int LD = 72;
    __shared__ unsigned short As[2][64][LD];
    __shared__ unsigned short Ws[2][64][LD];
    int bn = blockIdx.x * 64;
    int tid = threadIdx.x;
    int wid = tid >> 6, lane = tid & 63;
    int wm = (wid >> 1) * 32, wn = (wid & 1) * 32;
    int l15 = lane & 15, lg = lane >> 4;
    int r = tid >> 2, cq = (tid & 3) * 16;
    int gc = bn + r;

    auto load_w = [&](int k0, u32x4& p0, u32x4& p1) {
        p0 = (u32x4){}; p1 = (u32x4){};
        if (gc < kV) {
            const float* wr = W + (size_t)gc * kD + k0 + cq;
            float4 v0 = *(const float4*)(wr);
            float4 v1 = *(const float4*)(wr + 4);
            float4 v2 = *(const float4*)(wr + 8);
            float4 v3 = *(const float4*)(wr + 12);
            p0[0] = f2bf2(v0.x, v0.y); p0[1] = f2bf2(v0.z, v0.w);
            p0[2] = f2bf2(v1.x, v1.y); p0[3] = f2bf2(v1.z, v1.w);
            p1[0] = f2bf2(v2.x, v2.y); p1[1] = f2bf2(v2.z, v2.w);
            p1[2] = f2bf2(v3.x, v3.y); p1[3] = f2bf2(v3.z, v3.w);
        }
    };
    auto load_a = [&](int k0, int mt, us8v& v0, us8v& v1) {
        const unsigned short* ar = A + (size_t)(mt * 64 + r) * kD + k0 + cq;
        v0 = *(const us8v*)ar;
        v1 = *(const us8v*)(ar + 8);
    };

    f32x4v acc[6][4];
    #pragma unroll
    for (int i = 0; i < 6; ++i)
        #pragma unroll
        for (int j = 0; j < 4; ++j) acc[i][j] = (f32x4v){};

    u32x4 rw0, rw1;
    us8v ra0, ra1;
    load_w(0, rw0, rw1);
    load_a(0, 0, ra0, ra1);
    *(u32x4*)&Ws[0][r][cq]     = rw0;
    *(u32x4*)&Ws[0][r][cq + 8] = rw1;
    *(us8v*)&As[0][r][cq]      = ra0;
    *(us8v*)&As[0][r][cq + 8]  = ra1;
    __syncthreads();

    int acur = 0, wcur = 0;
    for (int k0 = 0; k0 < kD; k0 += 64) {
        bool morek = (k0 + 64) < kD;
        if (morek) load_w(k0 + 64, rw0, rw1);
        #pragma unroll
        for (int mt = 0; mt < 6; ++mt) {
            bool last = !morek && (mt == 5);
            if (!last) {
                int nmt = (mt == 5) ? 0 : mt + 1;
                int nk0 = (mt == 5) ? k0 + 64 : k0;
                load_a(nk0, nmt, ra0, ra1);
            }
            #pragma unroll
            for (int kc = 0; kc < 2; ++kc) {
                us8v af0 = *(const us8v*)&As[acur][wm + l15][kc * 32 + lg * 8];
                us8v af1 = *(const us8v*)&As[acur][wm + 16 + l15][kc * 32 + lg * 8];
                us8v wf0 = *(const us8v*)&Ws[wcur][wn + l15][kc * 32 + lg * 8];
                us8v wf1 = *(const us8v*)&Ws[wcur][wn + 16 + l15][kc * 32 + lg * 8];
                acc[mt][0] = mfma_bf16(af0, wf0, acc[mt][0]);
                acc[mt][1] = mfma_bf16(af0, wf1, acc[mt][1]);
                acc[mt][2] = mfma_bf16(af1, wf0, acc[mt][2]);
                acc[mt][3] = mfma_bf16(af1, wf1, acc[mt][3]);
            }
            if (!last) {
                *(us8v*)&As[acur ^ 1][r][cq]     = ra0;
                *(us8v*)&As[acur ^ 1][r][cq + 8] = ra1;
                if (mt == 5) {
                    *(u32x4*)&Ws[wcur ^ 1][r][cq]     = rw0;
                    *(u32x4*)&Ws[wcur ^ 1][r][cq + 8] = rw1;
                }
                __syncthreads();
                acur ^= 1;
                if (mt == 5) wcur ^= 1;
            }
        }
    }
    #pragma unroll
    for (int mt = 0; mt < 6; ++mt) {
        #pragma unroll
        for (int fi = 0; fi < 2; ++fi) {
            #pragma unroll
            for (int fj = 0; fj < 2; ++fj) {
                int col = bn + wn + fj * 16 + l15;
                if (col >= kV) continue;
                #pragma unroll
                for (int rr = 0; rr < 4; ++rr) {
                    int row = mt * 64 + wm + fi * 16 + lg * 4 + rr;
                    out[(size_t)row * kV + col] = acc[mt][fi * 2 + fj][rr];
                }
            }
        }
    }
}

// ========================================================================
// Attention scores via MFMA -> bf16 scratch (+fp32 cqk for cross)
// ========================================================================
template <int QBF>
__global__ __launch_bounds__(256)
void k_scores(const void* __restrict__ qv, const float* __restrict__ kk,
              unsigned short* __restrict__ sws, float* __restrict__ cqk,
              int Nk, int sld, int selfmask, int kPerB)
{
    constexpr int LD = 72;
    __shared__ unsigned short As[64][LD];
    __shared__ unsigned short Ks[64][LD];
    int z = blockIdx.z, b = z / kH, h = z % kH;
    int bm = blockIdx.x * 64, bn = blockIdx.y * 64;
    const float* kbase = kk + (kPerB ? (size_t)b * kMC * kD : 0) + (size_t)h * kDH;

    int tid = threadIdx.x;
    int r = tid >> 2, c0 = (tid & 3) * 16;
    {
        if (QBF) {
            const unsigned short* q = (const unsigned short*)qv;
            const unsigned short* qr =
                q + (size_t)(b * kMC + bm + r) * kD + h * kDH + c0;
            *(us8v*)&As[r][c0]     = *(const us8v*)qr;
            *(us8v*)&As[r][c0 + 8] = *(const us8v*)(qr + 8);
        } else {
            const float* q = (const float*)qv;
            const float* qr = q + (size_t)(b * kMC + bm + r) * kD + h * kDH + c0;
            float4 v0 = *(const float4*)(qr);
            float4 v1 = *(const float4*)(qr + 4);
            float4 v2 = *(const float4*)(qr + 8);
            float4 v3 = *(const float4*)(qr + 12);
            u32x4 p0, p1;
            p0[0] = f2bf2(v0.x, v0.y); p0[1] = f2bf2(v0.z, v0.w);
            p0[2] = f2bf2(v1.x, v1.y); p0[3] = f2bf2(v1.z, v1.w);
            p1[0] = f2bf2(v2.x, v2.y); p1[1] = f2bf2(v2.z, v2.w);
            p1[2] = f2bf2(v3.x, v3.y); p1[3] = f2bf2(v3.z, v3.w);
            *(u32x4*)&As[r][c0]     = p0;
            *(u32x4*)&As[r][c0 + 8] = p1;
        }
        int gk = bn + r;
        if (gk < Nk) {
            const float* kr = kbase + (size_t)gk * kD + c0;
            float4 v0 = *(const float4*)(kr);
            float4 v1 = *(const float4*)(kr + 4);
            float4 v2 = *(const float4*)(kr + 8);
            float4 v3 = *(const float4*)(kr + 12);
            u32x4 p0, p1;
            p0[0] = f2bf2(v0.x, v0.y); p0[1] = f2bf2(v0.z, v0.w);
            p0[2] = f2bf2(v1.x, v1.y); p0[3] = f2bf2(v1.z, v1.w);
            p1[0] = f2bf2(v2.x, v2.y); p1[1] = f2bf2(v2.z, v2.w);
            p1[2] = f2bf2(v3.x, v3.y); p1[3] = f2bf2(v3.z, v3.w);
            *(u32x4*)&Ks[r][c0]     = p0;
            *(u32x4*)&Ks[r][c0 + 8] = p1;
        } else {
            u32x4 zz = {};
            *(u32x4*)&Ks[r][c0]     = zz;
            *(u32x4*)&Ks[r][c0 + 8] = zz;
        }
    }
    __syncthreads();

    int wid = tid >> 6, lane = tid & 63;
    int wm = (wid >> 1) * 32, wn = (wid & 1) * 32;
    int l15 = lane & 15, lg = lane >> 4;

    f32x4v acc[2][2] = {};
    #pragma unroll
    for (int kc = 0; kc < 2; ++kc) {
        us8v a0 = *(const us8v*)&As[wm + l15][kc * 32 + lg * 8];
        us8v a1 = *(const us8v*)&As[wm + 16 + l15][kc * 32 + lg * 8];
        us8v b0 = *(const us8v*)&Ks[wn + l15][kc * 32 + lg * 8];
        us8v b1 = *(const us8v*)&Ks[wn + 16 + l15][kc * 32 + lg * 8];
        acc[0][0] = mfma_bf16(a0, b0, acc[0][0]);
        acc[0][1] = mfma_bf16(a0, b1, acc[0][1]);
        acc[1][0] = mfma_bf16(a1, b0, acc[1][0]);
        acc[1][1] = mfma_bf16(a1, b1, acc[1][1]);
    }

    #pragma unroll
    for (int fm = 0; fm < 2; ++fm) {
        #pragma unroll
        for (int fn = 0; fn < 2; ++fn) {
            int gj = bn + wn + fn * 16 + l15;
            if (gj >= Nk) continue;
            #pragma unroll
            for (int rr = 0; rr < 4; ++rr) {
                int gi = bm + wm + fm * 16 + lg * 4 + rr;
                float val = acc[fm][fn][rr] * kScale;
                if (cqk && gi < kT)
                    cqk[(((size_t)(b * kH + h)) * kT + gi) * kSA + gj] = val;
                if (selfmask && (gj > gi || gj >= kT)) val = -1e30f;
                sws[((size_t)z * kMC + gi) * sld + gj] = f2bf(val);
            }
        }
    }
}

// ========================================================================
// Softmax + PV via MFMA, bf16 scores. Block = 16 q-rows of one z.
// ========================================================================
constexpr int kCH  = 128;   // key chunk
constexpr int kLDK = 136;   // bf16 k-stride
__global__ __launch_bounds__(256)
void k_pv(const unsigned short* __restrict__ sws, const float* __restrict__ vv,
          unsigned short* __restrict__ o, int Nk, int sld, int vPerB)
{
    __shared__ unsigned short Pb[16][kLDK];
    __shared__ unsigned short Vt[64][kLDK];
    __shared__ float smx[16], sinv[16];
    int z = blockIdx.y, b = z / kH, h = z % kH;
    int i0 = blockIdx.x * 16;
    int t = threadIdx.x, wid = t >> 6, lane = t & 63;
    int l15 = lane & 15, lg = lane >> 4;
    const float* vbase = vv + (vPerB ? (size_t)b * kMC * kD : 0) + (size_t)h * kDH;

    // ---- pass 1: row max & inv-sum (vectorized 8-wide reads) ----
    for (int r2 = wid; r2 < 16; r2 += 4) {
        const unsigned short* srow2 = sws + ((size_t)z * kMC + i0 + r2) * sld;
        float mx = -3e38f;
        for (int j0 = lane * 8; j0 < Nk; j0 += 512) {
            us8v v = *(const us8v*)&srow2[j0];
            #pragma unroll
            for (int e = 0; e < 8; ++e)
                if (j0 + e < Nk) mx = fmaxf(mx, bf2f(v[e]));
        }
        for (int off = 32; off > 0; off >>= 1) mx = fmaxf(mx, __shfl_xor(mx, off));
        float sum = 0.f;
        for (int j0 = lane * 8; j0 < Nk; j0 += 512) {
            us8v v = *(const us8v*)&srow2[j0];
            #pragma unroll
            for (int e = 0; e < 8; ++e)
                if (j0 + e < Nk) sum += expf(bf2f(v[e]) - mx);
        }
        for (int off = 32; off > 0; off >>= 1) sum += __shfl_xor(sum, off);
        if (lane == 0) { smx[r2] = mx; sinv[r2] = 1.f / sum; }
    }
    __syncthreads();

    // ---- pass 2: chunked MFMA PV ----
    int pr = t >> 4;                 // P-stage row 0..15
    int jb = (t & 15) * 8;           // P-stage key base within chunk
    const unsigned short* srow = sws + ((size_t)z * kMC + i0 + pr) * sld;
    float mxv = smx[pr];

    f32x4v acc = {};
    for (int k0 = 0; k0 < Nk; k0 += kCH) {
        #pragma unroll
        for (int u = 0; u < 4; ++u) {
            int flat = t + u * 256;
            int kr = (flat >> 4) * 2;
            int c4 = flat & 15;
            float4 va = {0,0,0,0}, vb2 = {0,0,0,0};
            if (k0 + kr < Nk)
                va = *(const float4*)(vbase + (size_t)(k0 + kr) * kD + c4 * 4);
            if (k0 + kr + 1 < Nk)
                vb2 = *(const float4*)(vbase + (size_t)(k0 + kr + 1) * kD + c4 * 4);
            *(unsigned int*)&Vt[c4 * 4 + 0][kr] = f2bf2(va.x, vb2.x);
            *(unsigned int*)&Vt[c4 * 4 + 1][kr] = f2bf2(va.y, vb2.y);
            *(unsigned int*)&Vt[c4 * 4 + 2][kr] = f2bf2(va.z, vb2.z);
            *(unsigned int*)&Vt[c4 * 4 + 3][kr] = f2bf2(va.w, vb2.w);
        }
        {
            us8v praw = *(const us8v*)&srow[k0 + jb];
            #pragma unroll
            for (int u = 0; u < 8; u += 2) {
                int gj0 = k0 + jb + u;
                float e0 = (gj0     < Nk) ? expf(bf2f(praw[u])     - mxv) : 0.f;
                float e1 = (gj0 + 1 < Nk) ? expf(bf2f(praw[u + 1]) - mxv) : 0.f;
                *(unsigned int*)&Pb[pr][jb + u] = f2bf2(e0, e1);
            }
        }
        __syncthreads();
        #pragma unroll
        for (int kc = 0; kc < 4; ++kc) {
            us8v a  = *(const us8v*)&Pb[l15][kc * 32 + lg * 8];
            us8v bf = *(const us8v*)&Vt[wid * 16 + l15][kc * 32 + lg * 8];
            acc = mfma_bf16(a, bf, acc);
        }
        __syncthreads();
    }

    #pragma unroll
    for (int rr = 0; rr < 4; ++rr) {
        int row = lg * 4 + rr;
        float v = acc[rr] * sinv[row];
        o[(size_t)(b * kMC + i0 + row) * kD + h * kDH + wid * 16 + l15] = f2bf(v);
    }
}

// ========================================================================
extern "C" void kernel_launch(void* const* d_in, const int* in_sizes, int n_in,
                              void* d_out, int out_size, void* d_ws, size_t ws_size,
                              hipStream_t stream)
{
    const int*   x   = (const int*)  d_in[0];
    const float* xa  = (const float*)d_in[1];
    const float* tok = (const float*)d_in[4];
    const float* pos = (const float*)d_in[5];
    const float* attn_ln_g  = (const float*)d_in[6];
    const float* attn_ln_b  = (const float*)d_in[7];
    const float* attn_q_w   = (const float*)d_in[8];
    const float* attn_q_b   = (const float*)d_in[9];
    const float* attn_k_w   = (const float*)d_in[10];
    const float* attn_v_w   = (const float*)d_in[11];
    const float* attn_v_b   = (const float*)d_in[12];
    const float* attn_o_w   = (const float*)d_in[13];
    const float* attn_o_b   = (const float*)d_in[14];
    const float* cross_ln_g = (const float*)d_in[15];
    const float* cross_ln_b = (const float*)d_in[16];
    const float* cross_q_w  = (const float*)d_in[17];
    const float* cross_q_b  = (const float*)d_in[18];
    const float* cross_k_w  = (const float*)d_in[19];
    const float* cross_v_w  = (const float*)d_in[20];
    const float* cross_v_b  = (const float*)d_in[21];
    const float* cross_o_w  = (const float*)d_in[22];
    const float* cross_o_b  = (const float*)d_in[23];
    const float* mlp_ln_g   = (const float*)d_in[24];
    const float* mlp_ln_b   = (const float*)d_in[25];
    const float* mlp_w1     = (const float*)d_in[26];
    const float* mlp_b1     = (const float*)d_in[27];
    const float* mlp_w2     = (const float*)d_in[28];
    const float* mlp_b2     = (const float*)d_in[29];
    const float* ln_g       = (const float*)d_in[30];
    const float* ln_b       = (const float*)d_in[31];

    float* out = (float*)d_out;
    float* h    = (float*)d_ws;                          // 512*768 f32
    float* qws  = h   + (size_t)kR * kD;                 // 512*768 f32 (self q)
    unsigned short* sS    = (unsigned short*)(qws + (size_t)kR * kD); // bf16 scores
    unsigned short* y16   = sS   + (size_t)kB * kH * kMC * kSLDc;
    unsigned short* qb16  = y16  + (size_t)kR * kD;      // cross q bf16
    unsigned short* o16   = qb16 + (size_t)kR * kD;      // attn out bf16
    unsigned short* hid16 = o16  + (size_t)kR * kD;      // MLP hidden bf16
    unsigned short* yF16  = hid16 + (size_t)kR * 4 * kD; // final LN bf16
    unsigned short* xa16  = yF16 + (size_t)kB * kT * kD; // xa bf16 (1500*768)

    k_embed<<<kB * kMC * kD / 256, 256, 0, stream>>>(x, tok, pos, h);
    k_cvtbf<<<(kSA * kD / 8 + 255) / 256, 256, 0, stream>>>(xa, xa16, kSA * kD / 8);

    // all cross K/V projections (layer-invariant input xa, pre-cvt bf16)
    {
        GBatch gc{};
        for (int l = 0; l < kL; ++l) {
            gc.e[2 * l]     = { cross_k_w + (size_t)l * kD * kD, nullptr, nullptr,
                                out + OFF_CKV + (size_t)(2 * l) * kSA * kD };
            gc.e[2 * l + 1] = { cross_v_w + (size_t)l * kD * kD, cross_v_b + (size_t)l * kD,
                                nullptr,
                                out + OFF_CKV + (size_t)(2 * l + 1) * kSA * kD };
        }
        gemm_t<1, 0><<<dim3((kSA + 63) / 64, kD / 64, 2 * kL), 256, 0, stream>>>(
            xa16, gc, kSA, kD, kD, 0);
    }

    for (int l = 0; l < kL; ++l) {
        size_t dd = (size_t)l * kD * kD;
        float* kbuf  = out + OFF_MKV + (size_t)(2 * l)     * kB * kMC * kD;
        float* vbuf  = out + OFF_MKV + (size_t)(2 * l + 1) * kB * kMC * kD;
        float* ckbuf = out + OFF_CKV + (size_t)(2 * l)     * kSA * kD;
        float* cvbuf = out + OFF_CKV + (size_t)(2 * l + 1) * kSA * kD;
        float* cqk   = out + OFF_CQK + (size_t)l * kB * kH * kT * kSA;

        // --- self attention ---
        k_ln<<<kR, 256, 0, stream>>>(h, attn_ln_g + l * kD, attn_ln_b + l * kD, y16);
        {
            GBatch g3{};
            g3.e[0] = { attn_q_w + dd, attn_q_b + (size_t)l * kD, nullptr, qws };
            g3.e[1] = { attn_k_w + dd, nullptr,                   nullptr, kbuf };
            g3.e[2] = { attn_v_w + dd, attn_v_b + (size_t)l * kD, nullptr, vbuf };
            gemm32<0><<<dim3(kR / 32, kD / 64, 3), 256, 0, stream>>>(
                y16, g3, kR, kD, kD, 0);
        }
        k_scores<0><<<dim3(kMC / 64, kMC / 64, kB * kH), 256, 0, stream>>>(
            qws, kbuf, sS, nullptr, kMC, kMC, 1, 1);
        k_pv<<<dim3(kMC / 16, kB * kH), 256, 0, stream>>>(sS, vbuf, o16, kMC, kMC, 1);
        {
            GBatch g1{};
            g1.e[0] = { attn_o_w + dd, attn_o_b + (size_t)l * kD, h, h };
            gemm3232<0><<<dim3(kR / 32, kD / 32, 1), 256, 0, stream>>>(
                o16, g1, kR, kD, kD, 0);
        }

        // --- cross attention ---
        k_ln<<<kR, 256, 0, stream>>>(h, cross_ln_g + l * kD, cross_ln_b + l * kD, y16);
        {
            GBatch g1{};
            g1.e[0] = { cross_q_w + dd, cross_q_b + (size_t)l * kD, nullptr, qb16 };
            gemm3232<1><<<dim3(kR / 32, kD / 32, 1), 256, 0, stream>>>(
                y16, g1, kR, kD, kD, 0);
        }
        k_scores<1><<<dim3(kMC / 64, (kSA + 63) / 64, kB * kH), 256, 0, stream>>>(
            qb16, ckbuf, sS, cqk, kSA, kSLDc, 0, 0);
        k_pv<<<dim3(kMC / 16, kB * kH), 256, 0, stream>>>(sS, cvbuf, o16, kSA, kSLDc, 0);
        {
            GBatch g1{};
            g1.e[0] = { cross_o_w + dd, cross_o_b + (size_t)l * kD, h, h };
            gemm3232<0><<<dim3(kR / 32, kD / 32, 1), 256, 0, stream>>>(
                o16, g1, kR, kD, kD, 0);
        }

        // --- MLP ---
        k_ln<<<kR, 256, 0, stream>>>(h, mlp_ln_g + l * kD, mlp_ln_b + l * kD, y16);
        {
            GBatch g1{};
            g1.e[0] = { mlp_w1 + (size_t)l * 4 * kD * kD, mlp_b1 + (size_t)l * 4 * kD,
                        nullptr, hid16 };
            gemm32<1><<<dim3(kR / 32, 4 * kD / 64, 1), 256, 0, stream>>>(
                y16, g1, kR, 4 * kD, kD, 1);
        }
        {
            GBatch g1{};
            g1.e[0] = { mlp_w2 + (size_t)l * 4 * kD * kD, mlp_b2 + (size_t)l * kD, h, h };
            gemm3232<0><<<dim3(kR / 32, kD / 32, 1), 256, 0, stream>>>(
                hid16, g1, kR, kD, 4 * kD, 0);
        }
    }

    k_finalln<<<kB * kT, 256, 0, stream>>>(h, ln_g, ln_b, yF16);
    k_logits<<<dim3((kV + 63) / 64), 256, 0, stream>>>(yF16, tok, out);
}

// Round 19
// 2842.985 us; speedup vs baseline: 1.1945x; 1.0041x over previous
//
#include <hip/hip_runtime.h>
#include <math.h>

// ---- problem constants --------------------------------------------------
constexpr int kL = 12, kD = 768, kH = 12, kV = 51865, kSA = 1500;
constexpr int kB = 2, kT = 192, kMC = 256, kDH = 64;
constexpr float kScale = 0.125f;      // DH^-0.5
constexpr float kEps = 1e-5f;
constexpr int kR = kB * kMC;          // 512 rows through the layer stack
constexpr int kSLDc = 1504;           // cross score row stride (elements)

// ---- d_out layout (flat float32, reference return order) ---------------
constexpr size_t SZ_LOGITS = (size_t)kB * kT * kV;
constexpr size_t SZ_CQK    = (size_t)kL * kB * kH * kT * kSA;
constexpr size_t SZ_MKV    = (size_t)2 * kL * kB * kMC * kD;
constexpr size_t OFF_CQK = SZ_LOGITS;
constexpr size_t OFF_MKV = OFF_CQK + SZ_CQK;
constexpr size_t OFF_CKV = OFF_MKV + SZ_MKV;

typedef float f32x4v __attribute__((ext_vector_type(4)));
typedef unsigned short us8v __attribute__((ext_vector_type(8)));
typedef unsigned short us4v __attribute__((ext_vector_type(4)));
typedef unsigned int   u32x4 __attribute__((ext_vector_type(4)));

static __device__ __forceinline__ unsigned short f2bf(float f) {
    unsigned int u = __float_as_uint(f);
    u += 0x7fffu + ((u >> 16) & 1u);          // round-to-nearest-even
    return (unsigned short)(u >> 16);
}

// packed f32x2 -> bf16x2 (RNE), low half from `lo`
static __device__ __forceinline__ unsigned int f2bf2(float lo, float hi) {
    unsigned int r;
    asm("v_cvt_pk_bf16_f32 %0, %1, %2" : "=v"(r) : "v"(lo), "v"(hi));
    return r;
}

static __device__ __forceinline__ float bf2f(unsigned short u) {
    return __uint_as_float((unsigned int)u << 16);
}

static __device__ __forceinline__ f32x4v mfma_bf16(us8v a, us8v b, f32x4v c) {
    asm("v_mfma_f32_16x16x32_bf16 %0, %1, %2, %0" : "+v"(c) : "v"(a), "v"(b));
    return c;
}

// ========================================================================
// embedding
// ========================================================================
__global__ void k_embed(const int* __restrict__ x, const float* __restrict__ tok,
                        const float* __restrict__ pos, float* __restrict__ h)
{
    int idx = blockIdx.x * 256 + threadIdx.x;
    int d = idx % kD;
    int t = (idx / kD) % kMC;
    int b = idx / (kD * kMC);
    float v = 0.f;
    if (t < kT) {
        int tokid = x[b * kT + t];
        v = tok[(size_t)tokid * kD + d] + pos[(size_t)t * kD + d];
    }
    h[idx] = v;
}

// ========================================================================
// fp32 -> bf16 bulk conversion (RNE)
// ========================================================================
__global__ void k_cvtbf(const float* __restrict__ in,
                        unsigned short* __restrict__ out, int n8)
{
    int i = blockIdx.x * 256 + threadIdx.x;
    if (i >= n8) return;
    const float* p = in + (size_t)i * 8;
    float4 v0 = *(const float4*)(p);
    float4 v1 = *(const float4*)(p + 4);
    u32x4 q;
    q[0] = f2bf2(v0.x, v0.y); q[1] = f2bf2(v0.z, v0.w);
    q[2] = f2bf2(v1.x, v1.y); q[3] = f2bf2(v1.z, v1.w);
    *(u32x4*)&out[(size_t)i * 8] = q;
}

// ========================================================================
// LayerNorm (256 thr per row of 768) -> bf16 output
// ========================================================================
__global__ void k_ln(const float* __restrict__ in, const float* __restrict__ g,
                     const float* __restrict__ bb, unsigned short* __restrict__ out)
{
    int r = blockIdx.x;
    const float* xr = in + (size_t)r * kD;
    int t = threadIdx.x;
    float x0 = xr[t], x1 = xr[t + 256], x2 = xr[t + 512];
    float s  = x0 + x1 + x2;
    float sq = x0 * x0 + x1 * x1 + x2 * x2;
    __shared__ float red[8];
    for (int o = 32; o > 0; o >>= 1) { s += __shfl_down(s, o); sq += __shfl_down(sq, o); }
    int w = t >> 6;
    if ((t & 63) == 0) { red[w] = s; red[4 + w] = sq; }
    __syncthreads();
    s  = red[0] + red[1] + red[2] + red[3];
    sq = red[4] + red[5] + red[6] + red[7];
    float m   = s * (1.f / kD);
    float var = sq * (1.f / kD) - m * m;
    float rs  = rsqrtf(var + kEps);
    unsigned short* orow = out + (size_t)r * kD;
    orow[t]       = f2bf((x0 - m) * rs * g[t]       + bb[t]);
    orow[t + 256] = f2bf((x1 - m) * rs * g[t + 256] + bb[t + 256]);
    orow[t + 512] = f2bf((x2 - m) * rs * g[t + 512] + bb[t + 512]);
}

__global__ void k_finalln(const float* __restrict__ h, const float* __restrict__ g,
                          const float* __restrict__ bb, unsigned short* __restrict__ out)
{
    int r = blockIdx.x;                 // 0..kB*kT
    int b = r / kT, tt = r % kT;
    const float* xr = h + (size_t)(b * kMC + tt) * kD;
    int t = threadIdx.x;
    float x0 = xr[t], x1 = xr[t + 256], x2 = xr[t + 512];
    float s  = x0 + x1 + x2;
    float sq = x0 * x0 + x1 * x1 + x2 * x2;
    __shared__ float red[8];
    for (int o = 32; o > 0; o >>= 1) { s += __shfl_down(s, o); sq += __shfl_down(sq, o); }
    int w = t >> 6;
    if ((t & 63) == 0) { red[w] = s; red[4 + w] = sq; }
    __syncthreads();
    s  = red[0] + red[1] + red[2] + red[3];
    sq = red[4] + red[5] + red[6] + red[7];
    float m   = s * (1.f / kD);
    float var = sq * (1.f / kD) - m * m;
    float rs  = rsqrtf(var + kEps);
    unsigned short* orow = out + (size_t)r * kD;
    orow[t]       = f2bf((x0 - m) * rs * g[t]       + bb[t]);
    orow[t + 256] = f2bf((x1 - m) * rs * g[t + 256] + bb[t + 256]);
    orow[t + 512] = f2bf((x2 - m) * rs * g[t + 512] + bb[t + 512]);
}

// ========================================================================
// GEMM entry: obf selects bf16 (1) or fp32+residual (0) output at runtime
// (uniform per block; same rounding point either way).
// ========================================================================
struct GEntry { const float* W; const float* bias; const float* res; void* out; int obf; };
struct GBatch { GEntry e[24]; };

// ========================================================================
// bf16-MFMA GEMM (BM=64), triple-buffered, prefetch distance 2.
// Used for the bf16-A cross-K/V init batch.
// ========================================================================
template <int ABF>
__global__ __launch_bounds__(256)
void gemm_t(const void* __restrict__ Av, GBatch gb, int M, int N, int K,
            int dogelu)
{
    constexpr int LD = 72;
    __shared__ unsigned short As[3][64][LD];
    __shared__ unsigned short Ws[3][64][LD];
    const GEntry ge = gb.e[blockIdx.z];
    const float* __restrict__ W = ge.W;
    int bn = blockIdx.y * 64;
    int bm = blockIdx.x * 64;
    int tid = threadIdx.x;
    int wid = tid >> 6, lane = tid & 63;
    int wm = (wid >> 1) * 32, wn = (wid & 1) * 32;
    int l15 = lane & 15, lg = lane >> 4;
    int r = tid >> 2, cq = (tid & 3) * 16;
    int gr = bm + r, gc = bn + r;

    auto load_a = [&](int k0, u32x4& p0, u32x4& p1) {
        p0 = (u32x4){}; p1 = (u32x4){};
        if (ABF) {
            if (gr < M) {
                const unsigned short* ar =
                    (const unsigned short*)Av + (size_t)gr * K + k0 + cq;
                p0 = *(const u32x4*)ar;
                p1 = *(const u32x4*)(ar + 8);
            }
        } else {
            if (gr < M) {
                const float* ar = (const float*)Av + (size_t)gr * K + k0 + cq;
                float4 v0 = *(const float4*)(ar);
                float4 v1 = *(const float4*)(ar + 4);
                float4 v2 = *(const float4*)(ar + 8);
                float4 v3 = *(const float4*)(ar + 12);
                p0[0] = f2bf2(v0.x, v0.y); p0[1] = f2bf2(v0.z, v0.w);
                p0[2] = f2bf2(v1.x, v1.y); p0[3] = f2bf2(v1.z, v1.w);
                p1[0] = f2bf2(v2.x, v2.y); p1[1] = f2bf2(v2.z, v2.w);
                p1[2] = f2bf2(v3.x, v3.y); p1[3] = f2bf2(v3.z, v3.w);
            }
        }
    };
    auto load_w = [&](int k0, u32x4& p0, u32x4& p1) {
        p0 = (u32x4){}; p1 = (u32x4){};
        if (gc < N) {
            const float* wr = W + (size_t)gc * K + k0 + cq;
            float4 v0 = *(const float4*)(wr);
            float4 v1 = *(const float4*)(wr + 4);
            float4 v2 = *(const float4*)(wr + 8);
            float4 v3 = *(const float4*)(wr + 12);
            p0[0] = f2bf2(v0.x, v0.y); p0[1] = f2bf2(v0.z, v0.w);
            p0[2] = f2bf2(v1.x, v1.y); p0[3] = f2bf2(v1.z, v1.w);
            p1[0] = f2bf2(v2.x, v2.y); p1[1] = f2bf2(v2.z, v2.w);
            p1[2] = f2bf2(v3.x, v3.y); p1[3] = f2bf2(v3.z, v3.w);
        }
    };
    auto stage = [&](int buf, u32x4 a0, u32x4 a1, u32x4 w0, u32x4 w1) {
        *(u32x4*)&As[buf][r][cq]     = a0;
        *(u32x4*)&As[buf][r][cq + 8] = a1;
        *(u32x4*)&Ws[buf][r][cq]     = w0;
        *(u32x4*)&Ws[buf][r][cq + 8] = w1;
    };

    f32x4v acc00 = {}, acc01 = {}, acc10 = {}, acc11 = {};
    auto domfma = [&](int buf) {
        #pragma unroll
        for (int kc = 0; kc < 2; ++kc) {
            us8v af0 = *(const us8v*)&As[buf][wm + l15][kc * 32 + lg * 8];
            us8v af1 = *(const us8v*)&As[buf][wm + 16 + l15][kc * 32 + lg * 8];
            us8v wf0 = *(const us8v*)&Ws[buf][wn + l15][kc * 32 + lg * 8];
            us8v wf1 = *(const us8v*)&Ws[buf][wn + 16 + l15][kc * 32 + lg * 8];
            acc00 = mfma_bf16(af0, wf0, acc00);
            acc01 = mfma_bf16(af0, wf1, acc01);
            acc10 = mfma_bf16(af1, wf0, acc10);
            acc11 = mfma_bf16(af1, wf1, acc11);
        }
    };

    u32x4 a0A, a1A, w0A, w1A, a0B, a1B, w0B, w1B;
    load_a(0, a0A, a1A); load_w(0, w0A, w1A);
    stage(0, a0A, a1A, w0A, w1A);
    load_a(64, a0B, a1B); load_w(64, w0B, w1B);
    __syncthreads();

    int cur = 0;
    for (int k0 = 0; k0 < K; k0 += 128) {
        int n1 = cur + 1; if (n1 == 3) n1 = 0;
        int n2 = n1 + 1; if (n2 == 3) n2 = 0;
        if (k0 + 128 < K) { load_a(k0 + 128, a0A, a1A); load_w(k0 + 128, w0A, w1A); }
        domfma(cur);
        stage(n1, a0B, a1B, w0B, w1B);
        __syncthreads();
        if (k0 + 192 < K) { load_a(k0 + 192, a0B, a1B); load_w(k0 + 192, w0B, w1B); }
        domfma(n1);
        if (k0 + 128 < K) {
            stage(n2, a0A, a1A, w0A, w1A);
            __syncthreads();
        }
        cur = n2;
    }

    const float* bias = ge.bias;
    const float* res  = ge.res;
    f32x4v accs[2][2] = { { acc00, acc01 }, { acc10, acc11 } };
    #pragma unroll
    for (int fi = 0; fi < 2; ++fi) {
        #pragma unroll
        for (int fj = 0; fj < 2; ++fj) {
            int col = bn + wn + fj * 16 + l15;
            if (col >= N) continue;
            float bv = bias ? bias[col] : 0.f;
            #pragma unroll
            for (int rr = 0; rr < 4; ++rr) {
                int row = bm + wm + fi * 16 + lg * 4 + rr;
                if (row >= M) continue;
                float v = accs[fi][fj][rr] + bv;
                if (dogelu) v = 0.5f * v * (1.f + erff(v * 0.70710678118654752f));
                if (ge.obf) {
                    ((unsigned short*)ge.out)[(size_t)row * N + col] = f2bf(v);
                } else {
                    if (res) v += res[(size_t)row * N + col];
                    ((float*)ge.out)[(size_t)row * N + col] = v;
                }
            }
        }
    }
}

// ========================================================================
// bf16-MFMA GEMM, BM=32/BN=64 (2x block count), triple-buffered.
// ========================================================================
__global__ __launch_bounds__(256)
void gemm32(const unsigned short* __restrict__ A, GBatch gb, int M, int N, int K,
            int dogelu)
{
    constexpr int LD = 72;
    __shared__ unsigned short As[3][32][LD];
    __shared__ unsigned short Ws[3][64][LD];
    const GEntry ge = gb.e[blockIdx.z];
    const float* __restrict__ W = ge.W;
    int bn = blockIdx.y * 64;
    int bm = blockIdx.x * 32;
    int tid = threadIdx.x;
    int wid = tid >> 6, lane = tid & 63;
    int wr = (wid >> 1) * 16, wc = (wid & 1) * 32;
    int l15 = lane & 15, lg = lane >> 4;
    int ra = tid >> 3, ca = (tid & 7) * 8;    // A staging: 32 rows x 64 k
    int rw = tid >> 2, cw = (tid & 3) * 16;   // W staging: 64 rows x 64 k
    int gr = bm + ra, gc = bn + rw;

    auto load_a = [&](int k0, us8v& p) {
        p = (us8v){};
        if (gr < M) p = *(const us8v*)(A + (size_t)gr * K + k0 + ca);
    };
    auto load_w = [&](int k0, u32x4& p0, u32x4& p1) {
        p0 = (u32x4){}; p1 = (u32x4){};
        if (gc < N) {
            const float* wrp = W + (size_t)gc * K + k0 + cw;
            float4 v0 = *(const float4*)(wrp);
            float4 v1 = *(const float4*)(wrp + 4);
            float4 v2 = *(const float4*)(wrp + 8);
            float4 v3 = *(const float4*)(wrp + 12);
            p0[0] = f2bf2(v0.x, v0.y); p0[1] = f2bf2(v0.z, v0.w);
            p0[2] = f2bf2(v1.x, v1.y); p0[3] = f2bf2(v1.z, v1.w);
            p1[0] = f2bf2(v2.x, v2.y); p1[1] = f2bf2(v2.z, v2.w);
            p1[2] = f2bf2(v3.x, v3.y); p1[3] = f2bf2(v3.z, v3.w);
        }
    };
    auto stage = [&](int buf, us8v a, u32x4 w0, u32x4 w1) {
        *(us8v*)&As[buf][ra][ca]      = a;
        *(u32x4*)&Ws[buf][rw][cw]     = w0;
        *(u32x4*)&Ws[buf][rw][cw + 8] = w1;
    };

    f32x4v acc0 = {}, acc1 = {};
    auto domfma = [&](int buf) {
        #pragma unroll
        for (int kc = 0; kc < 2; ++kc) {
            us8v af  = *(const us8v*)&As[buf][wr + l15][kc * 32 + lg * 8];
            us8v wf0 = *(const us8v*)&Ws[buf][wc + l15][kc * 32 + lg * 8];
            us8v wf1 = *(const us8v*)&Ws[buf][wc + 16 + l15][kc * 32 + lg * 8];
            acc0 = mfma_bf16(af, wf0, acc0);
            acc1 = mfma_bf16(af, wf1, acc1);
        }
    };

    us8v aA, aB;
    u32x4 w0A, w1A, w0B, w1B;
    load_a(0, aA); load_w(0, w0A, w1A);
    stage(0, aA, w0A, w1A);
    load_a(64, aB); load_w(64, w0B, w1B);
    __syncthreads();

    int cur = 0;
    for (int k0 = 0; k0 < K; k0 += 128) {
        int n1 = cur + 1; if (n1 == 3) n1 = 0;
        int n2 = n1 + 1; if (n2 == 3) n2 = 0;
        if (k0 + 128 < K) { load_a(k0 + 128, aA); load_w(k0 + 128, w0A, w1A); }
        domfma(cur);
        stage(n1, aB, w0B, w1B);
        __syncthreads();
        if (k0 + 192 < K) { load_a(k0 + 192, aB); load_w(k0 + 192, w0B, w1B); }
        domfma(n1);
        if (k0 + 128 < K) {
            stage(n2, aA, w0A, w1A);
            __syncthreads();
        }
        cur = n2;
    }

    const float* bias = ge.bias;
    const float* res  = ge.res;
    f32x4v accs[2] = { acc0, acc1 };
    #pragma unroll
    for (int fj = 0; fj < 2; ++fj) {
        int col = bn + wc + fj * 16 + l15;
        if (col >= N) continue;
        float bv = bias ? bias[col] : 0.f;
        #pragma unroll
        for (int rr = 0; rr < 4; ++rr) {
            int row = bm + wr + lg * 4 + rr;
            if (row >= M) continue;
            float v = accs[fj][rr] + bv;
            if (dogelu) v = 0.5f * v * (1.f + erff(v * 0.70710678118654752f));
            if (ge.obf) {
                ((unsigned short*)ge.out)[(size_t)row * N + col] = f2bf(v);
            } else {
                if (res) v += res[(size_t)row * N + col];
                ((float*)ge.out)[(size_t)row * N + col] = v;
            }
        }
    }
}

// ========================================================================
// bf16-MFMA GEMM, BM=32/BN=32 (4x block count) for 192-block launches.
// ========================================================================
__global__ __launch_bounds__(256)
void gemm3232(const unsigned short* __restrict__ A, GBatch gb, int M, int N, int K,
              int dogelu)
{
    constexpr int LD = 72;
    __shared__ unsigned short As[3][32][LD];
    __shared__ unsigned short Ws[3][32][LD];
    const GEntry ge = gb.e[blockIdx.z];
    const float* __restrict__ W = ge.W;
    int bn = blockIdx.y * 32;
    int bm = blockIdx.x * 32;
    int tid = threadIdx.x;
    int wid = tid >> 6, lane = tid & 63;
    int wr = (wid >> 1) * 16, wc = (wid & 1) * 16;
    int l15 = lane & 15, lg = lane >> 4;
    int ra = tid >> 3, ca = (tid & 7) * 8;    // staging: 32 rows x 64 k
    int gr = bm + ra, gc = bn + ra;

    auto load_a = [&](int k0, us8v& p) {
        p = (us8v){};
        if (gr < M) p = *(const us8v*)(A + (size_t)gr * K + k0 + ca);
    };
    auto load_w = [&](int k0, u32x4& p) {
        p = (u32x4){};
        if (gc < N) {
            const float* wrp = W + (size_t)gc * K + k0 + ca;
            float4 v0 = *(const float4*)(wrp);
            float4 v1 = *(const float4*)(wrp + 4);
            p[0] = f2bf2(v0.x, v0.y); p[1] = f2bf2(v0.z, v0.w);
            p[2] = f2bf2(v1.x, v1.y); p[3] = f2bf2(v1.z, v1.w);
        }
    };
    auto stage = [&](int buf, us8v a, u32x4 w) {
        *(us8v*)&As[buf][ra][ca]  = a;
        *(u32x4*)&Ws[buf][ra][ca] = w;
    };

    f32x4v acc = {};
    auto domfma = [&](int buf) {
        #pragma unroll
        for (int kc = 0; kc < 2; ++kc) {
            us8v af = *(const us8v*)&As[buf][wr + l15][kc * 32 + lg * 8];
            us8v wf = *(const us8v*)&Ws[buf][wc + l15][kc * 32 + lg * 8];
            acc = mfma_bf16(af, wf, acc);
        }
    };

    us8v aA, aB;
    u32x4 wA, wB;
    load_a(0, aA); load_w(0, wA);
    stage(0, aA, wA);
    load_a(64, aB); load_w(64, wB);
    __syncthreads();

    int cur = 0;
    for (int k0 = 0; k0 < K; k0 += 128) {
        int n1 = cur + 1; if (n1 == 3) n1 = 0;
        int n2 = n1 + 1; if (n2 == 3) n2 = 0;
        if (k0 + 128 < K) { load_a(k0 + 128, aA); load_w(k0 + 128, wA); }
        domfma(cur);
        stage(n1, aB, wB);
        __syncthreads();
        if (k0 + 192 < K) { load_a(k0 + 192, aB); load_w(k0 + 192, wB); }
        domfma(n1);
        if (k0 + 128 < K) {
            stage(n2, aA, wA);
            __syncthreads();
        }
        cur = n2;
    }

    const float* bias = ge.bias;
    const float* res  = ge.res;
    {
        int col = bn + wc + l15;
        if (col < N) {
            float bv = bias ? bias[col] : 0.f;
            #pragma unroll
            for (int rr = 0; rr < 4; ++rr) {
                int row = bm + wr + lg * 4 + rr;
                if (row >= M) continue;
                float v = acc[rr] + bv;
                if (dogelu) v = 0.5f * v * (1.f + erff(v * 0.70710678118654752f));
                if (ge.obf) {
                    ((unsigned short*)ge.out)[(size_t)row * N + col] = f2bf(v);
                } else {
                    if (res) v += res[(size_t)row * N + col];
                    ((float*)ge.out)[(size_t)row * N + col] = v;
                }
            }
        }
    }
}

// ========================================================================
// Logits GEMM: k0-outer / m-tile-inner, W AND A double-buffered.
// ========================================================================
__global__ __launch_bounds__(256)
void k_logits(const unsigned short* __restrict__ A, const float* __restrict__ W,
              float* __restrict__ out)
{
    constexpr int LD = 72;
    __shared__ unsigned short As[2][64][LD];
    __shared__ unsigned short Ws[2][64][LD];
    int bn = blockIdx.x * 64;
    int tid = threadIdx.x;
    int wid = tid >> 6, lane = tid & 63;
    int wm = (wid >> 1) * 32, wn = (wid & 1) * 32;
    int l15 = lane & 15, lg = lane >> 4;
    int r = tid >> 2, cq = (tid & 3) * 16;
    int gc = bn + r;

    auto load_w = [&](int k0, u32x4& p0, u32x4& p1) {
        p0 = (u32x4){}; p1 = (u32x4){};
        if (gc < kV) {
            const float* wr = W + (size_t)gc * kD + k0 + cq;
            float4 v0 = *(const float4*)(wr);
            float4 v1 = *(const float4*)(wr + 4);
            float4 v2 = *(const float4*)(wr + 8);
            float4 v3 = *(const float4*)(wr + 12);
            p0[0] = f2bf2(v0.x, v0.y); p0[1] = f2bf2(v0.z, v0.w);
            p0[2] = f2bf2(v1.x, v1.y); p0[3] = f2bf2(v1.z, v1.w);
            p1[0] = f2bf2(v2.x, v2.y); p1[1] = f2bf2(v2.z, v2.w);
            p1[2] = f2bf2(v3.x, v3.y); p1[3] = f2bf2(v3.z, v3.w);
        }
    };
    auto load_a = [&](int k0, int mt, us8v& v0, us8v& v1) {
        const unsigned short* ar = A + (size_t)(mt * 64 + r) * kD + k0 + cq;
        v0 = *(const us8v*)ar;
        v1 = *(const us8v*)(ar + 8);
    };

    f32x4v acc[6][4];
    #pragma unroll
    for (int i = 0; i < 6; ++i)
        #pragma unroll
        for (int j = 0; j < 4; ++j) acc[i][j] = (f32x4v){};

    u32x4 rw0, rw1;
    us8v ra0, ra1;
    load_w(0, rw0, rw1);
    load_a(0, 0, ra0, ra1);
    *(u32x4*)&Ws[0][r][cq]     = rw0;
    *(u32x4*)&Ws[0][r][cq + 8] = rw1;
    *(us8v*)&As[0][r][cq]      = ra0;
    *(us8v*)&As[0][r][cq + 8]  = ra1;
    __syncthreads();

    int acur = 0, wcur = 0;
    for (int k0 = 0; k0 < kD; k0 += 64) {
        bool morek = (k0 + 64) < kD;
        if (morek) load_w(k0 + 64, rw0, rw1);
        #pragma unroll
        for (int mt = 0; mt < 6; ++mt) {
            bool last = !morek && (mt == 5);
            if (!last) {
                int nmt = (mt == 5) ? 0 : mt + 1;
                int nk0 = (mt == 5) ? k0 + 64 : k0;
                load_a(nk0, nmt, ra0, ra1);
            }
            #pragma unroll
            for (int kc = 0; kc < 2; ++kc) {
                us8v af0 = *(const us8v*)&As[acur][wm + l15][kc * 32 + lg * 8];
                us8v af1 = *(const us8v*)&As[acur][wm + 16 + l15][kc * 32 + lg * 8];
                us8v wf0 = *(const us8v*)&Ws[wcur][wn + l15][kc * 32 + lg * 8];
                us8v wf1 = *(const us8v*)&Ws[wcur][wn + 16 + l15][kc * 32 + lg * 8];
                acc[mt][0] = mfma_bf16(af0, wf0, acc[mt][0]);
                acc[mt][1] = mfma_bf16(af0, wf1, acc[mt][1]);
                acc[mt][2] = mfma_bf16(af1, wf0, acc[mt][2]);
                acc[mt][3] = mfma_bf16(af1, wf1, acc[mt][3]);
            }
            if (!last) {
                *(us8v*)&As[acur ^ 1][r][cq]     = ra0;
                *(us8v*)&As[acur ^ 1][r][cq + 8] = ra1;
                if (mt == 5) {
                    *(u32x4*)&Ws[wcur ^ 1][r][cq]     = rw0;
                    *(u32x4*)&Ws[wcur ^ 1][r][cq + 8] = rw1;
                }
                __syncthreads();
                acur ^= 1;
                if (mt == 5) wcur ^= 1;
            }
        }
    }
    #pragma unroll
    for (int mt = 0; mt < 6; ++mt) {
        #pragma unroll
        for (int fi = 0; fi < 2; ++fi) {
            #pragma unroll
            for (int fj = 0; fj < 2; ++fj) {
                int col = bn + wn + fj * 16 + l15;
                if (col >= kV) continue;
                #pragma unroll
                for (int rr = 0; rr < 4; ++rr) {
                    int row = mt * 64 + wm + fi * 16 + lg * 4 + rr;
                    out[(size_t)row * kV + col] = acc[mt][fi * 2 + fj][rr];
                }
            }
        }
    }
}

// ========================================================================
// Attention scores via MFMA -> bf16 scratch (+fp32 cqk for cross).
// Q is bf16 (both self and cross now).
// ========================================================================
__global__ __launch_bounds__(256)
void k_scores(const unsigned short* __restrict__ q, const float* __restrict__ kk,
              unsigned short* __restrict__ sws, float* __restrict__ cqk,
              int Nk, int sld, int selfmask, int kPerB)
{
    constexpr int LD = 72;
    __shared__ unsigned short As[64][LD];
    __shared__ unsigned short Ks[64][LD];
    int z = blockIdx.z, b = z / kH, h = z % kH;
    int bm = blockIdx.x * 64, bn = blockIdx.y * 64;
    const float* kbase = kk + (kPerB ? (size_t)b * kMC * kD : 0) + (size_t)h * kDH;

    int tid = threadIdx.x;
    int r = tid >> 2, c0 = (tid & 3) * 16;
    {
        const unsigned short* qr =
            q + (size_t)(b * kMC + bm + r) * kD + h * kDH + c0;
        *(us8v*)&As[r][c0]     = *(const us8v*)qr;
        *(us8v*)&As[r][c0 + 8] = *(const us8v*)(qr + 8);

        int gk = bn + r;
        if (gk < Nk) {
            const float* kr = kbase + (size_t)gk * kD + c0;
            float4 v0 = *(const float4*)(kr);
            float4 v1 = *(const float4*)(kr + 4);
            float4 v2 = *(const float4*)(kr + 8);
            float4 v3 = *(const float4*)(kr + 12);
            u32x4 p0, p1;
            p0[0] = f2bf2(v0.x, v0.y); p0[1] = f2bf2(v0.z, v0.w);
            p0[2] = f2bf2(v1.x, v1.y); p0[3] = f2bf2(v1.z, v1.w);
            p1[0] = f2bf2(v2.x, v2.y); p1[1] = f2bf2(v2.z, v2.w);
            p1[2] = f2bf2(v3.x, v3.y); p1[3] = f2bf2(v3.z, v3.w);
            *(u32x4*)&Ks[r][c0]     = p0;
            *(u32x4*)&Ks[r][c0 + 8] = p1;
        } else {
            u32x4 zz = {};
            *(u32x4*)&Ks[r][c0]     = zz;
            *(u32x4*)&Ks[r][c0 + 8] = zz;
        }
    }
    __syncthreads();

    int wid = tid >> 6, lane = tid & 63;
    int wm = (wid >> 1) * 32, wn = (wid & 1) * 32;
    int l15 = lane & 15, lg = lane >> 4;

    f32x4v acc[2][2] = {};
    #pragma unroll
    for (int kc = 0; kc < 2; ++kc) {
        us8v a0 = *(const us8v*)&As[wm + l15][kc * 32 + lg * 8];
        us8v a1 = *(const us8v*)&As[wm + 16 + l15][kc * 32 + lg * 8];
        us8v b0 = *(const us8v*)&Ks[wn + l15][kc * 32 + lg * 8];
        us8v b1 = *(const us8v*)&Ks[wn + 16 + l15][kc * 32 + lg * 8];
        acc[0][0] = mfma_bf16(a0, b0, acc[0][0]);
        acc[0][1] = mfma_bf16(a0, b1, acc[0][1]);
        acc[1][0] = mfma_bf16(a1, b0, acc[1][0]);
        acc[1][1] = mfma_bf16(a1, b1, acc[1][1]);
    }

    #pragma unroll
    for (int fm = 0; fm < 2; ++fm) {
        #pragma unroll
        for (int fn = 0; fn < 2; ++fn) {
            int gj = bn + wn + fn * 16 + l15;
            if (gj >= Nk) continue;
            #pragma unroll
            for (int rr = 0; rr < 4; ++rr) {
                int gi = bm + wm + fm * 16 + lg * 4 + rr;
                float val = acc[fm][fn][rr] * kScale;
                if (cqk && gi < kT)
                    cqk[(((size_t)(b * kH + h)) * kT + gi) * kSA + gj] = val;
                if (selfmask && (gj > gi || gj >= kT)) val = -1e30f;
                sws[((size_t)z * kMC + gi) * sld + gj] = f2bf(val);
            }
        }
    }
}

// ========================================================================
// Softmax + PV via MFMA, bf16 scores. Block = 16 q-rows of one z.
// ========================================================================
constexpr int kCH  = 128;   // key chunk
constexpr int kLDK = 136;   // bf16 k-stride
__global__ __launch_bounds__(256)
void k_pv(const unsigned short* __restrict__ sws, const float* __restrict__ vv,
          unsigned short* __restrict__ o, int Nk, int sld, int vPerB)
{
    __shared__ unsigned short Pb[16][kLDK];
    __shared__ unsigned short Vt[64][kLDK];
    __shared__ float smx[16], sinv[16];
    int z = blockIdx.y, b = z / kH, h = z % kH;
    int i0 = blockIdx.x * 16;
    int t = threadIdx.x, wid = t >> 6, lane = t & 63;
    int l15 = lane & 15, lg = lane >> 4;
    const float* vbase = vv + (vPerB ? (size_t)b * kMC * kD : 0) + (size_t)h * kDH;

    // ---- pass 1: row max & inv-sum (vectorized 8-wide reads) ----
    for (int r2 = wid; r2 < 16; r2 += 4) {
        const unsigned short* srow2 = sws + ((size_t)z * kMC + i0 + r2) * sld;
        float mx = -3e38f;
        for (int j0 = lane * 8; j0 < Nk; j0 += 512) {
            us8v v = *(const us8v*)&srow2[j0];
            #pragma unroll
            for (int e = 0; e < 8; ++e)
                if (j0 + e < Nk) mx = fmaxf(mx, bf2f(v[e]));
        }
        for (int off = 32; off > 0; off >>= 1) mx = fmaxf(mx, __shfl_xor(mx, off));
        float sum = 0.f;
        for (int j0 = lane * 8; j0 < Nk; j0 += 512) {
            us8v v = *(const us8v*)&srow2[j0];
            #pragma unroll
            for (int e = 0; e < 8; ++e)
                if (j0 + e < Nk) sum += expf(bf2f(v[e]) - mx);
        }
        for (int off = 32; off > 0; off >>= 1) sum += __shfl_xor(sum, off);
        if (lane == 0) { smx[r2] = mx; sinv[r2] = 1.f / sum; }
    }
    __syncthreads();

    // ---- pass 2: chunked MFMA PV ----
    int pr = t >> 4;                 // P-stage row 0..15
    int jb = (t & 15) * 8;           // P-stage key base within chunk
    const unsigned short* srow = sws + ((size_t)z * kMC + i0 + pr) * sld;
    float mxv = smx[pr];

    f32x4v acc = {};
    for (int k0 = 0; k0 < Nk; k0 += kCH) {
        #pragma unroll
        for (int u = 0; u < 4; ++u) {
            int flat = t + u * 256;
            int kr = (flat >> 4) * 2;
            int c4 = flat & 15;
            float4 va = {0,0,0,0}, vb2 = {0,0,0,0};
            if (k0 + kr < Nk)
                va = *(const float4*)(vbase + (size_t)(k0 + kr) * kD + c4 * 4);
            if (k0 + kr + 1 < Nk)
                vb2 = *(const float4*)(vbase + (size_t)(k0 + kr + 1) * kD + c4 * 4);
            *(unsigned int*)&Vt[c4 * 4 + 0][kr] = f2bf2(va.x, vb2.x);
            *(unsigned int*)&Vt[c4 * 4 + 1][kr] = f2bf2(va.y, vb2.y);
            *(unsigned int*)&Vt[c4 * 4 + 2][kr] = f2bf2(va.z, vb2.z);
            *(unsigned int*)&Vt[c4 * 4 + 3][kr] = f2bf2(va.w, vb2.w);
        }
        {
            us8v praw = *(const us8v*)&srow[k0 + jb];
            #pragma unroll
            for (int u = 0; u < 8; u += 2) {
                int gj0 = k0 + jb + u;
                float e0 = (gj0     < Nk) ? expf(bf2f(praw[u])     - mxv) : 0.f;
                float e1 = (gj0 + 1 < Nk) ? expf(bf2f(praw[u + 1]) - mxv) : 0.f;
                *(unsigned int*)&Pb[pr][jb + u] = f2bf2(e0, e1);
            }
        }
        __syncthreads();
        #pragma unroll
        for (int kc = 0; kc < 4; ++kc) {
            us8v a  = *(const us8v*)&Pb[l15][kc * 32 + lg * 8];
            us8v bf = *(const us8v*)&Vt[wid * 16 + l15][kc * 32 + lg * 8];
            acc = mfma_bf16(a, bf, acc);
        }
        __syncthreads();
    }

    #pragma unroll
    for (int rr = 0; rr < 4; ++rr) {
        int row = lg * 4 + rr;
        float v = acc[rr] * sinv[row];
        o[(size_t)(b * kMC + i0 + row) * kD + h * kDH + wid * 16 + l15] = f2bf(v);
    }
}

// ========================================================================
extern "C" void kernel_launch(void* const* d_in, const int* in_sizes, int n_in,
                              void* d_out, int out_size, void* d_ws, size_t ws_size,
                              hipStream_t stream)
{
    const int*   x   = (const int*)  d_in[0];
    const float* xa  = (const float*)d_in[1];
    const float* tok = (const float*)d_in[4];
    const float* pos = (const float*)d_in[5];
    const float* attn_ln_g  = (const float*)d_in[6];
    const float* attn_ln_b  = (const float*)d_in[7];
    const float* attn_q_w   = (const float*)d_in[8];
    const float* attn_q_b   = (const float*)d_in[9];
    const float* attn_k_w   = (const float*)d_in[10];
    const float* attn_v_w   = (const float*)d_in[11];
    const float* attn_v_b   = (const float*)d_in[12];
    const float* attn_o_w   = (const float*)d_in[13];
    const float* attn_o_b   = (const float*)d_in[14];
    const float* cross_ln_g = (const float*)d_in[15];
    const float* cross_ln_b = (const float*)d_in[16];
    const float* cross_q_w  = (const float*)d_in[17];
    const float* cross_q_b  = (const float*)d_in[18];
    const float* cross_k_w  = (const float*)d_in[19];
    const float* cross_v_w  = (const float*)d_in[20];
    const float* cross_v_b  = (const float*)d_in[21];
    const float* cross_o_w  = (const float*)d_in[22];
    const float* cross_o_b  = (const float*)d_in[23];
    const float* mlp_ln_g   = (const float*)d_in[24];
    const float* mlp_ln_b   = (const float*)d_in[25];
    const float* mlp_w1     = (const float*)d_in[26];
    const float* mlp_b1     = (const float*)d_in[27];
    const float* mlp_w2     = (const float*)d_in[28];
    const float* mlp_b2     = (const float*)d_in[29];
    const float* ln_g       = (const float*)d_in[30];
    const float* ln_b       = (const float*)d_in[31];

    float* out = (float*)d_out;
    float* h    = (float*)d_ws;                          // 512*768 f32
    unsigned short* sS    = (unsigned short*)(h + (size_t)kR * kD);   // bf16 scores
    unsigned short* y16   = sS   + (size_t)kB * kH * kMC * kSLDc;
    unsigned short* qb16  = y16  + (size_t)kR * kD;      // q bf16 (self & cross)
    unsigned short* o16   = qb16 + (size_t)kR * kD;      // attn out bf16
    unsigned short* hid16 = o16  + (size_t)kR * kD;      // MLP hidden bf16
    unsigned short* yF16  = hid16 + (size_t)kR * 4 * kD; // final LN bf16
    unsigned short* xa16  = yF16 + (size_t)kB * kT * kD; // xa bf16 (1500*768)

    k_embed<<<kB * kMC * kD / 256, 256, 0, stream>>>(x, tok, pos, h);
    k_cvtbf<<<(kSA * kD / 8 + 255) / 256, 256, 0, stream>>>(xa, xa16, kSA * kD / 8);

    // all cross K/V projections (layer-invariant input xa, pre-cvt bf16)
    {
        GBatch gc{};
        for (int l = 0; l < kL; ++l) {
            gc.e[2 * l]     = { cross_k_w + (size_t)l * kD * kD, nullptr, nullptr,
                                out + OFF_CKV + (size_t)(2 * l) * kSA * kD, 0 };
            gc.e[2 * l + 1] = { cross_v_w + (size_t)l * kD * kD, cross_v_b + (size_t)l * kD,
                                nullptr,
                                out + OFF_CKV + (size_t)(2 * l + 1) * kSA * kD, 0 };
        }
        gemm_t<1><<<dim3((kSA + 63) / 64, kD / 64, 2 * kL), 256, 0, stream>>>(
            xa16, gc, kSA, kD, kD, 0);
    }

    for (int l = 0; l < kL; ++l) {
        size_t dd = (size_t)l * kD * kD;
        float* kbuf  = out + OFF_MKV + (size_t)(2 * l)     * kB * kMC * kD;
        float* vbuf  = out + OFF_MKV + (size_t)(2 * l + 1) * kB * kMC * kD;
        float* ckbuf = out + OFF_CKV + (size_t)(2 * l)     * kSA * kD;
        float* cvbuf = out + OFF_CKV + (size_t)(2 * l + 1) * kSA * kD;
        float* cqk   = out + OFF_CQK + (size_t)l * kB * kH * kT * kSA;

        // --- self attention (q written directly as bf16: same rounding) ---
        k_ln<<<kR, 256, 0, stream>>>(h, attn_ln_g + l * kD, attn_ln_b + l * kD, y16);
        {
            GBatch g3{};
            g3.e[0] = { attn_q_w + dd, attn_q_b + (size_t)l * kD, nullptr, qb16, 1 };
            g3.e[1] = { attn_k_w + dd, nullptr,                   nullptr, kbuf, 0 };
            g3.e[2] = { attn_v_w + dd, attn_v_b + (size_t)l * kD, nullptr, vbuf, 0 };
            gemm32<<<dim3(kR / 32, kD / 64, 3), 256, 0, stream>>>(
                y16, g3, kR, kD, kD, 0);
        }
        k_scores<<<dim3(kMC / 64, kMC / 64, kB * kH), 256, 0, stream>>>(
            qb16, kbuf, sS, nullptr, kMC, kMC, 1, 1);
        k_pv<<<dim3(kMC / 16, kB * kH), 256, 0, stream>>>(sS, vbuf, o16, kMC, kMC, 1);
        {
            GBatch g1{};
            g1.e[0] = { attn_o_w + dd, attn_o_b + (size_t)l * kD, h, h, 0 };
            gemm3232<<<dim3(kR / 32, kD / 32, 1), 256, 0, stream>>>(
                o16, g1, kR, kD, kD, 0);
        }

        // --- cross attention ---
        k_ln<<<kR, 256, 0, stream>>>(h, cross_ln_g + l * kD, cross_ln_b + l * kD, y16);
        {
            GBatch g1{};
            g1.e[0] = { cross_q_w + dd, cross_q_b + (size_t)l * kD, nullptr, qb16, 1 };
            gemm3232<<<dim3(kR / 32, kD / 32, 1), 256, 0, stream>>>(
                y16, g1, kR, kD, kD, 0);
        }
        k_scores<<<dim3(kMC / 64, (kSA + 63) / 64, kB * kH), 256, 0, stream>>>(
            qb16, ckbuf, sS, cqk, kSA, kSLDc, 0, 0);
        k_pv<<<dim3(kMC / 16, kB * kH), 256, 0, stream>>>(sS, cvbuf, o16, kSA, kSLDc, 0);
        {
            GBatch g1{};
            g1.e[0] = { cross_o_w + dd, cross_o_b + (size_t)l * kD, h, h, 0 };
            gemm3232<<<dim3(kR / 32, kD / 32, 1), 256, 0, stream>>>(
                o16, g1, kR, kD, kD, 0);
        }

        // --- MLP ---
        k_ln<<<kR, 256, 0, stream>>>(h, mlp_ln_g + l * kD, mlp_ln_b + l * kD, y16);
        {
            GBatch g1{};
            g1.e[0] = { mlp_w1 + (size_t)l * 4 * kD * kD, mlp_b1 + (size_t)l * 4 * kD,
                        nullptr, hid16, 1 };
            gemm32<<<dim3(kR / 32, 4 * kD / 64, 1), 256, 0, stream>>>(
                y16, g1, kR, 4 * kD, kD, 1);
        }
        {
            GBatch g1{};
            g1.e[0] = { mlp_w2 + (size_t)l * 4 * kD * kD, mlp_b2 + (size_t)l * kD, h, h, 0 };
            gemm3232<<<dim3(kR / 32, kD / 32, 1), 256, 0, stream>>>(
                hid16, g1, kR, kD, 4 * kD, 0);
        }
    }

    k_finalln<<<kB * kT, 256, 0, stream>>>(h, ln_g, ln_b, yF16);
    k_logits<<<dim3((kV + 63) / 64), 256, 0, stream>>>(yF16, tok, out);
}